// Round 2
// 1788.039 us; speedup vs baseline: 1.2341x; 1.2341x over previous
//
#include <hip/hip_runtime.h>

typedef unsigned short u16;
typedef unsigned int u32;

#define N_NODES 100000
#define IN_CH 512
#define HID_CH 256
#define CAP_E 3200000

typedef short bf16x8 __attribute__((ext_vector_type(8)));
typedef float f32x4 __attribute__((ext_vector_type(4)));

__device__ __forceinline__ float b2f(u16 u) {
  union { u32 i; float f; } v; v.i = ((u32)u) << 16; return v.f;
}
__device__ __forceinline__ u16 f2b(float f) {
  union { float f; u32 i; } v; v.f = f;
  u32 r = v.i + 0x7fffu + ((v.i >> 16) & 1u);
  return (u16)(r >> 16);
}

struct TyBF {}; struct TyF32 {};
template<class T> struct IsF32;
template<> struct IsF32<TyBF>  { static constexpr int v = 0; };
template<> struct IsF32<TyF32> { static constexpr int v = 1; };

template<class T> __device__ __forceinline__ float ldv(const void* p, size_t i);
template<> __device__ __forceinline__ float ldv<TyBF>(const void* p, size_t i) {
  return b2f(((const u16*)p)[i]);
}
template<> __device__ __forceinline__ float ldv<TyF32>(const void* p, size_t i) {
  return ((const float*)p)[i];
}
template<class T> __device__ __forceinline__ void stv(void* p, size_t i, float v);
template<> __device__ __forceinline__ void stv<TyBF>(void* p, size_t i, float v) {
  ((u16*)p)[i] = f2b(v);
}
template<> __device__ __forceinline__ void stv<TyF32>(void* p, size_t i, float v) {
  ((float*)p)[i] = v;
}

// ---------------- runtime dtype probes ----------------
// flags[0]: 1 if float tensors are fp32, 0 if bf16
// flags[1]: 1 if edge_index is int32, 0 if int64 (read as int32 pairs)

__global__ void detect_kernel(const u32* __restrict__ xw, const int* __restrict__ ei,
                              int* __restrict__ flags) {
  __shared__ int c1, c2;
  int t = threadIdx.x;  // 256
  if (t == 0) { c1 = 0; c2 = 0; }
  __syncthreads();
  u32 w = xw[t];
  int e = (w >> 7) & 0xFF;
  if (e >= 110 && e <= 135) atomicAdd(&c1, 1);
  if (ei[2 * t + 1] != 0) atomicAdd(&c2, 1);
  __syncthreads();
  if (t == 0) {
    flags[0] = (c1 < 154) ? 1 : 0;
    flags[1] = (c2 > 0) ? 1 : 0;
  }
}

// ---------------- graph build (CSR) ----------------

__global__ void count_kernel(const int* __restrict__ ei, const int* __restrict__ flags,
                             int* __restrict__ cnt, int E) {
  int e = blockIdx.x * blockDim.x + threadIdx.x;
  if (e >= E) return;
  int s, d;
  if (flags[1]) { s = ei[e]; d = ei[E + e]; }
  else          { s = ei[2 * e]; d = ei[2 * (E + e)]; }
  if ((u32)s >= N_NODES || (u32)d >= N_NODES) return;
  atomicAdd(&cnt[d], 1);
}

__global__ __launch_bounds__(256) void scan_kernel(const int* __restrict__ cnt,
                                                   int* __restrict__ offs) {
  __shared__ int sums[256];
  __shared__ int carry;
  int t = threadIdx.x;
  if (t == 0) carry = 0;
  __syncthreads();
  const int CHUNK = 256 * 16;
  for (int base = 0; base < N_NODES; base += CHUNK) {
    int lo = base + t * 16;
    int v[16];
    int sum = 0;
#pragma unroll
    for (int j = 0; j < 16; ++j) {
      int i = lo + j;
      v[j] = (i < N_NODES) ? cnt[i] : 0;
      sum += v[j];
    }
    sums[t] = sum;
    __syncthreads();
    for (int ds = 1; ds < 256; ds <<= 1) {
      int add = (t >= ds) ? sums[t - ds] : 0;
      __syncthreads();
      sums[t] += add;
      __syncthreads();
    }
    int excl = carry + sums[t] - sum;
#pragma unroll
    for (int j = 0; j < 16; ++j) {
      int i = lo + j;
      if (i < N_NODES) offs[i] = excl;
      excl += v[j];
    }
    __syncthreads();
    if (t == 255) carry += sums[255];
    __syncthreads();
  }
}

__global__ void fill_kernel(const int* __restrict__ ei, const int* __restrict__ flags,
                            const int* __restrict__ offs, int* __restrict__ cursor,
                            int* __restrict__ adj, int E) {
  int e = blockIdx.x * blockDim.x + threadIdx.x;
  if (e >= E) return;
  int s, d;
  if (flags[1]) { s = ei[e]; d = ei[E + e]; }
  else          { s = ei[2 * e]; d = ei[2 * (E + e)]; }
  if ((u32)s >= N_NODES || (u32)d >= N_NODES) return;
  int pos = atomicAdd(&cursor[d], 1);
  adj[offs[d] + pos] = s;
}

__global__ void dinv_kernel(const int* __restrict__ cnt, float* __restrict__ dinv, int n) {
  int i = blockIdx.x * blockDim.x + threadIdx.x;
  if (i >= n) return;
  dinv[i] = rsqrtf((float)(cnt[i] + 1));
}

// ---------------- MFMA GEMM 1: hx = x @ W1 ----------------
// 128x128 tile, BK=32, 4 waves (2x2), each wave 64x64 = 4x4 frags of 16x16x32.
// fp32 mode: A split into hi+lo bf16 planes (x-rounding error removed);
// W1 rounded to bf16 (error ~half of output-rounding error).
// LDS layout: As[plane][row][40], Bs[n][40] (k-minor, 80B row stride = 5*16B,
// 16B-aligned frag reads, ~2-way bank pattern = free).

template<class T>
__global__ __launch_bounds__(256) void mfma_gemm1(const void* __restrict__ x,
                                                  const void* __restrict__ W1,
                                                  u16* __restrict__ hx,
                                                  const int* __restrict__ flags) {
  if (flags[0] != IsF32<T>::v) return;
  constexpr int PA = IsF32<T>::v ? 2 : 1;
  __shared__ __align__(16) u16 As[PA][128][40];
  __shared__ __align__(16) u16 Bs[128][40];
  const int t = threadIdx.x;
  const int rowBase = blockIdx.y * 128;
  const int colBase = blockIdx.x * 128;
  const int lane = t & 63;
  const int wid = t >> 6;
  const int wm = (wid >> 1) * 64;
  const int wn = (wid & 1) * 64;
  const int fr = lane & 15;
  const int kc = lane >> 4;

  f32x4 acc[4][4] = {};

  for (int kt = 0; kt < IN_CH / 32; ++kt) {
    // ---- stage A tile (128 rows x 32 k) ----
    {
      int row = t >> 1;
      int c0 = (t & 1) * 16;
      int r = rowBase + row; if (r >= N_NODES) r = N_NODES - 1;
      size_t gb = (size_t)r * IN_CH + kt * 32 + c0;
      if (IsF32<T>::v) {
        u16 th[16], tl[16];
        const float* xp = (const float*)x + gb;
#pragma unroll
        for (int q = 0; q < 4; ++q) {
          float4 v = *(const float4*)(xp + 4 * q);
          float vv[4] = {v.x, v.y, v.z, v.w};
#pragma unroll
          for (int j = 0; j < 4; ++j) {
            u16 hb = f2b(vv[j]);
            th[4 * q + j] = hb;
            tl[4 * q + j] = f2b(vv[j] - b2f(hb));
          }
        }
        *(uint4*)&As[0][row][c0]     = *(uint4*)&th[0];
        *(uint4*)&As[0][row][c0 + 8] = *(uint4*)&th[8];
        *(uint4*)&As[1][row][c0]     = *(uint4*)&tl[0];
        *(uint4*)&As[1][row][c0 + 8] = *(uint4*)&tl[8];
      } else {
        const u16* xp = (const u16*)x + gb;
        *(uint4*)&As[0][row][c0]     = *(const uint4*)(xp);
        *(uint4*)&As[0][row][c0 + 8] = *(const uint4*)(xp + 8);
      }
    }
    // ---- stage B tile (32 k x 128 n) -> Bs[n][k] ----
    if (IsF32<T>::v) {
      for (int i = t; i < 1024; i += 256) {
        int k = i >> 5, g = i & 31;
        const float* p = (const float*)W1 + ((size_t)(kt * 32 + k) * HID_CH + colBase + g * 4);
        float4 v = *(const float4*)p;
        float vv[4] = {v.x, v.y, v.z, v.w};
#pragma unroll
        for (int j = 0; j < 4; ++j) Bs[g * 4 + j][k] = f2b(vv[j]);
      }
    } else {
      for (int i = t; i < 512; i += 256) {
        int k = i >> 4, g = i & 15;
        uint4 v = *(const uint4*)((const u16*)W1 + ((size_t)(kt * 32 + k) * HID_CH + colBase + g * 8));
        const u16* pv = (const u16*)&v;
#pragma unroll
        for (int j = 0; j < 8; ++j) Bs[g * 8 + j][k] = pv[j];
      }
    }
    __syncthreads();
    // ---- fragments + MFMA ----
    bf16x8 b[4];
#pragma unroll
    for (int ni = 0; ni < 4; ++ni)
      b[ni] = *(const bf16x8*)&Bs[wn + ni * 16 + fr][kc * 8];
#pragma unroll
    for (int mi = 0; mi < 4; ++mi) {
      bf16x8 a0 = *(const bf16x8*)&As[0][wm + mi * 16 + fr][kc * 8];
#pragma unroll
      for (int ni = 0; ni < 4; ++ni)
        acc[mi][ni] = __builtin_amdgcn_mfma_f32_16x16x32_bf16(a0, b[ni], acc[mi][ni], 0, 0, 0);
      if (IsF32<T>::v) {
        bf16x8 a1 = *(const bf16x8*)&As[1][wm + mi * 16 + fr][kc * 8];
#pragma unroll
        for (int ni = 0; ni < 4; ++ni)
          acc[mi][ni] = __builtin_amdgcn_mfma_f32_16x16x32_bf16(a1, b[ni], acc[mi][ni], 0, 0, 0);
      }
    }
    __syncthreads();
  }
  // ---- epilogue: C/D layout col=lane&15, row=(lane>>4)*4+j ----
#pragma unroll
  for (int mi = 0; mi < 4; ++mi) {
#pragma unroll
    for (int ni = 0; ni < 4; ++ni) {
#pragma unroll
      for (int j = 0; j < 4; ++j) {
        int row = rowBase + wm + mi * 16 + kc * 4 + j;
        if (row < N_NODES) {
          int col = colBase + wn + ni * 16 + fr;
          hx[(size_t)row * HID_CH + col] = f2b(acc[mi][ni][j]);
        }
      }
    }
  }
}

// ---------------- MFMA GEMM 2: hml = h @ [Wmu | Wlv] ----------------
// A = h is bf16 (exact). fp32 mode: B split into hi+lo planes -> numerically
// equivalent to fp32 weights.

template<class T>
__global__ __launch_bounds__(256) void mfma_gemm2(const u16* __restrict__ h,
                                                  const void* __restrict__ Wmu,
                                                  const void* __restrict__ Wlv,
                                                  u16* __restrict__ hml,
                                                  const int* __restrict__ flags) {
  if (flags[0] != IsF32<T>::v) return;
  constexpr int PB = IsF32<T>::v ? 2 : 1;
  __shared__ __align__(16) u16 As[128][40];
  __shared__ __align__(16) u16 Bs[PB][128][40];
  const int t = threadIdx.x;
  const int rowBase = blockIdx.y * 128;
  const int lane = t & 63;
  const int wid = t >> 6;
  const int wm = (wid >> 1) * 64;
  const int wn = (wid & 1) * 64;
  const int fr = lane & 15;
  const int kc = lane >> 4;

  f32x4 acc[4][4] = {};

  for (int kt = 0; kt < HID_CH / 32; ++kt) {
    // ---- stage A tile (128 x 32) from h ----
    {
      int row = t >> 1;
      int c0 = (t & 1) * 16;
      int r = rowBase + row; if (r >= N_NODES) r = N_NODES - 1;
      const u16* hp = h + (size_t)r * HID_CH + kt * 32 + c0;
      *(uint4*)&As[row][c0]     = *(const uint4*)(hp);
      *(uint4*)&As[row][c0 + 8] = *(const uint4*)(hp + 8);
    }
    // ---- stage B tile (32 k x 128 n): n<64 -> Wmu col n, else Wlv col n-64 ----
    for (int i = t; i < 4096; i += 256) {
      int k = i >> 7, n = i & 127;
      const void* W = (n < 64) ? Wmu : Wlv;
      size_t idx = (size_t)(kt * 32 + k) * 64 + (n & 63);
      if (IsF32<T>::v) {
        float v = ((const float*)W)[idx];
        u16 hb = f2b(v);
        Bs[0][n][k] = hb;
        Bs[1][n][k] = f2b(v - b2f(hb));
      } else {
        Bs[0][n][k] = ((const u16*)W)[idx];
      }
    }
    __syncthreads();
    bf16x8 a[4];
#pragma unroll
    for (int mi = 0; mi < 4; ++mi)
      a[mi] = *(const bf16x8*)&As[wm + mi * 16 + fr][kc * 8];
#pragma unroll
    for (int ni = 0; ni < 4; ++ni) {
      bf16x8 b0 = *(const bf16x8*)&Bs[0][wn + ni * 16 + fr][kc * 8];
#pragma unroll
      for (int mi = 0; mi < 4; ++mi)
        acc[mi][ni] = __builtin_amdgcn_mfma_f32_16x16x32_bf16(a[mi], b0, acc[mi][ni], 0, 0, 0);
      if (IsF32<T>::v) {
        bf16x8 b1 = *(const bf16x8*)&Bs[1][wn + ni * 16 + fr][kc * 8];
#pragma unroll
        for (int mi = 0; mi < 4; ++mi)
          acc[mi][ni] = __builtin_amdgcn_mfma_f32_16x16x32_bf16(a[mi], b1, acc[mi][ni], 0, 0, 0);
      }
    }
    __syncthreads();
  }
#pragma unroll
  for (int mi = 0; mi < 4; ++mi) {
#pragma unroll
    for (int ni = 0; ni < 4; ++ni) {
#pragma unroll
      for (int j = 0; j < 4; ++j) {
        int row = rowBase + wm + mi * 16 + kc * 4 + j;
        if (row < N_NODES) {
          int col = wn + ni * 16 + fr;
          hml[(size_t)row * 128 + col] = f2b(acc[mi][ni][j]);
        }
      }
    }
  }
}

// ---------------- aggregation 1 (256 ch) + bias + relu -> h ----------------

template<class T>
__global__ __launch_bounds__(256) void agg1_kernel(const u16* __restrict__ hx,
                                                   const int* __restrict__ cnt,
                                                   const int* __restrict__ offs,
                                                   const int* __restrict__ adj,
                                                   const float* __restrict__ dinv,
                                                   const void* __restrict__ b1,
                                                   u16* __restrict__ h,
                                                   const int* __restrict__ flags) {
  if (flags[0] != IsF32<T>::v) return;
  int d = blockIdx.x * 4 + (threadIdx.x >> 6);
  if (d >= N_NODES) return;
  int lane = threadIdx.x & 63;
  int c = lane * 4;
  float a0 = 0.f, a1 = 0.f, a2 = 0.f, a3 = 0.f;
  int n = cnt[d];
  float dv = dinv[d];
  const int* ent = adj + offs[d];
  for (int j = 0; j < n; ++j) {
    int s = ent[j];
    float w = dv * dinv[s];
    const u16* p = hx + (size_t)s * HID_CH + c;
    a0 += w * b2f(p[0]); a1 += w * b2f(p[1]);
    a2 += w * b2f(p[2]); a3 += w * b2f(p[3]);
  }
  {
    float w = dv * dv;
    const u16* p = hx + (size_t)d * HID_CH + c;
    a0 += w * b2f(p[0]); a1 += w * b2f(p[1]);
    a2 += w * b2f(p[2]); a3 += w * b2f(p[3]);
  }
  a0 = fmaxf(a0 + ldv<T>(b1, c), 0.f);
  a1 = fmaxf(a1 + ldv<T>(b1, c + 1), 0.f);
  a2 = fmaxf(a2 + ldv<T>(b1, c + 2), 0.f);
  a3 = fmaxf(a3 + ldv<T>(b1, c + 3), 0.f);
  u16* q = h + (size_t)d * HID_CH + c;
  q[0] = f2b(a0); q[1] = f2b(a1); q[2] = f2b(a2); q[3] = f2b(a3);
}

// ---------------- aggregation 2 (128 ch) + bias + reparam ----------------

template<class T>
__global__ __launch_bounds__(256) void agg2_kernel(const u16* __restrict__ hml,
                                                   const int* __restrict__ cnt,
                                                   const int* __restrict__ offs,
                                                   const int* __restrict__ adj,
                                                   const float* __restrict__ dinv,
                                                   const void* __restrict__ bmu,
                                                   const void* __restrict__ blv,
                                                   const void* __restrict__ eps,
                                                   void* __restrict__ mu_out,
                                                   void* __restrict__ lv_out,
                                                   u16* __restrict__ z,
                                                   const int* __restrict__ flags) {
  if (flags[0] != IsF32<T>::v) return;
  int d = blockIdx.x * 4 + (threadIdx.x >> 6);
  if (d >= N_NODES) return;
  int lane = threadIdx.x & 63;
  float am = 0.f, al = 0.f;
  int n = cnt[d];
  float dv = dinv[d];
  const int* ent = adj + offs[d];
  for (int j = 0; j < n; ++j) {
    int s = ent[j];
    float w = dv * dinv[s];
    am += w * b2f(hml[(size_t)s * 128 + lane]);
    al += w * b2f(hml[(size_t)s * 128 + 64 + lane]);
  }
  {
    float w = dv * dv;
    am += w * b2f(hml[(size_t)d * 128 + lane]);
    al += w * b2f(hml[(size_t)d * 128 + 64 + lane]);
  }
  am += ldv<T>(bmu, lane);
  al += ldv<T>(blv, lane);
  size_t o = (size_t)d * 64 + lane;
  stv<T>(mu_out, o, am);
  stv<T>(lv_out, o, al);
  float zz = am + ldv<T>(eps, o) * expf(0.5f * al);
  z[o] = f2b(zz);
}

// ---------------- final small GEMM: out = z @ Wc + bc ----------------

template<class T>
__global__ __launch_bounds__(256) void out_gemm(const u16* __restrict__ z,
                                                const void* __restrict__ Wc,
                                                const void* __restrict__ bc,
                                                void* __restrict__ out,
                                                const int* __restrict__ flags) {
  if (flags[0] != IsF32<T>::v) return;
  __shared__ float Wcs[64][65];
  __shared__ float zs[4][65];
  int t = threadIdx.x;
  for (int i = t; i < 4096; i += 256) Wcs[i >> 6][i & 63] = ldv<T>(Wc, i);
  int ln = t >> 6;
  int col = t & 63;
  int node = blockIdx.x * 4 + ln;
  zs[ln][col] = b2f(z[(size_t)node * 64 + col]);
  __syncthreads();
  float acc = ldv<T>(bc, col);
#pragma unroll
  for (int k = 0; k < 64; ++k) acc += zs[ln][k] * Wcs[k][col];
  stv<T>(out, (size_t)node * 64 + col, acc);
}

// ---------------- launch ----------------

extern "C" void kernel_launch(void* const* d_in, const int* in_sizes, int n_in,
                              void* d_out, int out_size, void* d_ws, size_t ws_size,
                              hipStream_t stream) {
  const void* x   = d_in[0];
  const int*  ei  = (const int*)d_in[1];
  const void* W1  = d_in[2];
  const void* b1  = d_in[3];
  const void* Wmu = d_in[4];
  const void* bmu = d_in[5];
  const void* Wlv = d_in[6];
  const void* blv = d_in[7];
  const void* Wc  = d_in[8];
  const void* bc  = d_in[9];
  const void* eps = d_in[10];
  int E = in_sizes[1] / 2;

  char* ws = (char*)d_ws;
  int*   flags  = (int*)(ws);                    // 64 B
  int*   cnt    = (int*)(ws + 1024);             // 400 KB
  int*   cursor = (int*)(ws + (512 << 10));      // 400 KB
  int*   offs   = (int*)(ws + (1 << 20));        // 400 KB
  float* dinv   = (float*)(ws + (1536 << 10));   // 400 KB
  int*   adj    = (int*)(ws + (2 << 20));        // 12.8 MB
  size_t hx_off = (2 << 20) + (size_t)CAP_E * 4;
  u16* hx  = (u16*)(ws + hx_off);                                  // 51.2 MB
  u16* h   = (u16*)(ws + hx_off + (size_t)N_NODES * HID_CH * 2);   // 51.2 MB
  u16* hml = hx;  // hx dead after agg1; reuse (25.6 MB)
  u16* z   = (u16*)(ws + hx_off + (size_t)N_NODES * 128 * 2);      // 12.8 MB

  hipMemsetAsync(ws, 0, 2 << 20, stream);

  detect_kernel<<<1, 256, 0, stream>>>((const u32*)x, ei, flags);
  count_kernel<<<(E + 255) / 256, 256, 0, stream>>>(ei, flags, cnt, E);
  scan_kernel<<<1, 256, 0, stream>>>(cnt, offs);
  fill_kernel<<<(E + 255) / 256, 256, 0, stream>>>(ei, flags, offs, cursor, adj, E);
  dinv_kernel<<<(N_NODES + 255) / 256, 256, 0, stream>>>(cnt, dinv, N_NODES);

  // hx = x @ W1  (MFMA; grid.x = column tiles so row-tile pairs are L2-adjacent)
  {
    dim3 g1(2, (N_NODES + 127) / 128);
    mfma_gemm1<TyBF ><<<g1, 256, 0, stream>>>(x, W1, hx, flags);
    mfma_gemm1<TyF32><<<g1, 256, 0, stream>>>(x, W1, hx, flags);
  }

  // h = relu(agg(hx) + b1)
  agg1_kernel<TyBF ><<<N_NODES / 4, 256, 0, stream>>>(hx, cnt, offs, adj, dinv, b1, h, flags);
  agg1_kernel<TyF32><<<N_NODES / 4, 256, 0, stream>>>(hx, cnt, offs, adj, dinv, b1, h, flags);

  // hml = h @ [Wmu | Wlv]  (MFMA)
  {
    dim3 g2(1, (N_NODES + 127) / 128);
    mfma_gemm2<TyBF ><<<g2, 256, 0, stream>>>(h, Wmu, Wlv, hml, flags);
    mfma_gemm2<TyF32><<<g2, 256, 0, stream>>>(h, Wmu, Wlv, hml, flags);
  }

  // mu, logvar, z
  {
    char* ob = (char*)d_out;
    size_t esz_bf = 2, esz_f32 = 4;
    void* mu_bf  = ob + (size_t)N_NODES * 64 * esz_bf;
    void* lv_bf  = ob + (size_t)N_NODES * 128 * esz_bf;
    void* mu_f32 = ob + (size_t)N_NODES * 64 * esz_f32;
    void* lv_f32 = ob + (size_t)N_NODES * 128 * esz_f32;
    agg2_kernel<TyBF ><<<N_NODES / 4, 256, 0, stream>>>(hml, cnt, offs, adj, dinv, bmu, blv,
                                                        eps, mu_bf, lv_bf, z, flags);
    agg2_kernel<TyF32><<<N_NODES / 4, 256, 0, stream>>>(hml, cnt, offs, adj, dinv, bmu, blv,
                                                        eps, mu_f32, lv_f32, z, flags);
  }

  // out = z @ Wc + bc
  out_gemm<TyBF ><<<N_NODES / 4, 256, 0, stream>>>(z, Wc, bc, d_out, flags);
  out_gemm<TyF32><<<N_NODES / 4, 256, 0, stream>>>(z, Wc, bc, d_out, flags);
}

// Round 3
// 1401.224 us; speedup vs baseline: 1.5748x; 1.2761x over previous
//
#include <hip/hip_runtime.h>

typedef unsigned short u16;
typedef unsigned int u32;

#define N_NODES 100000
#define IN_CH 512
#define HID_CH 256
#define CAP_E 3200000

typedef short bf16x8 __attribute__((ext_vector_type(8)));
typedef float f32x4 __attribute__((ext_vector_type(4)));

__device__ __forceinline__ float b2f(u16 u) {
  union { u32 i; float f; } v; v.i = ((u32)u) << 16; return v.f;
}
__device__ __forceinline__ u16 f2b(float f) {
  union { float f; u32 i; } v; v.f = f;
  u32 r = v.i + 0x7fffu + ((v.i >> 16) & 1u);
  return (u16)(r >> 16);
}

struct TyBF {}; struct TyF32 {};
template<class T> struct IsF32;
template<> struct IsF32<TyBF>  { static constexpr int v = 0; };
template<> struct IsF32<TyF32> { static constexpr int v = 1; };

template<class T> __device__ __forceinline__ float ldv(const void* p, size_t i);
template<> __device__ __forceinline__ float ldv<TyBF>(const void* p, size_t i) {
  return b2f(((const u16*)p)[i]);
}
template<> __device__ __forceinline__ float ldv<TyF32>(const void* p, size_t i) {
  return ((const float*)p)[i];
}
template<class T> __device__ __forceinline__ void stv(void* p, size_t i, float v);
template<> __device__ __forceinline__ void stv<TyBF>(void* p, size_t i, float v) {
  ((u16*)p)[i] = f2b(v);
}
template<> __device__ __forceinline__ void stv<TyF32>(void* p, size_t i, float v) {
  ((float*)p)[i] = v;
}

// ---------------- runtime dtype probes ----------------

__global__ void detect_kernel(const u32* __restrict__ xw, const int* __restrict__ ei,
                              int* __restrict__ flags) {
  __shared__ int c1, c2;
  int t = threadIdx.x;  // 256
  if (t == 0) { c1 = 0; c2 = 0; }
  __syncthreads();
  u32 w = xw[t];
  int e = (w >> 7) & 0xFF;
  if (e >= 110 && e <= 135) atomicAdd(&c1, 1);
  if (ei[2 * t + 1] != 0) atomicAdd(&c2, 1);
  __syncthreads();
  if (t == 0) {
    flags[0] = (c1 < 154) ? 1 : 0;
    flags[1] = (c2 > 0) ? 1 : 0;
  }
}

// ---------------- graph build (CSR) ----------------

__global__ void count_kernel(const int* __restrict__ ei, const int* __restrict__ flags,
                             int* __restrict__ cnt, int E) {
  int e = blockIdx.x * blockDim.x + threadIdx.x;
  if (e >= E) return;
  int s, d;
  if (flags[1]) { s = ei[e]; d = ei[E + e]; }
  else          { s = ei[2 * e]; d = ei[2 * (E + e)]; }
  if ((u32)s >= N_NODES || (u32)d >= N_NODES) return;
  atomicAdd(&cnt[d], 1);
}

__global__ __launch_bounds__(256) void scan_kernel(const int* __restrict__ cnt,
                                                   int* __restrict__ offs) {
  __shared__ int sums[256];
  __shared__ int carry;
  int t = threadIdx.x;
  if (t == 0) carry = 0;
  __syncthreads();
  const int CHUNK = 256 * 16;
  for (int base = 0; base < N_NODES; base += CHUNK) {
    int lo = base + t * 16;
    int v[16];
    int sum = 0;
#pragma unroll
    for (int j = 0; j < 16; ++j) {
      int i = lo + j;
      v[j] = (i < N_NODES) ? cnt[i] : 0;
      sum += v[j];
    }
    sums[t] = sum;
    __syncthreads();
    for (int ds = 1; ds < 256; ds <<= 1) {
      int add = (t >= ds) ? sums[t - ds] : 0;
      __syncthreads();
      sums[t] += add;
      __syncthreads();
    }
    int excl = carry + sums[t] - sum;
#pragma unroll
    for (int j = 0; j < 16; ++j) {
      int i = lo + j;
      if (i < N_NODES) offs[i] = excl;
      excl += v[j];
    }
    __syncthreads();
    if (t == 255) carry += sums[255];
    __syncthreads();
  }
}

__global__ void fill_kernel(const int* __restrict__ ei, const int* __restrict__ flags,
                            const int* __restrict__ offs, int* __restrict__ cursor,
                            int* __restrict__ adj, int E) {
  int e = blockIdx.x * blockDim.x + threadIdx.x;
  if (e >= E) return;
  int s, d;
  if (flags[1]) { s = ei[e]; d = ei[E + e]; }
  else          { s = ei[2 * e]; d = ei[2 * (E + e)]; }
  if ((u32)s >= N_NODES || (u32)d >= N_NODES) return;
  int pos = atomicAdd(&cursor[d], 1);
  adj[offs[d] + pos] = s;
}

__global__ void dinv_kernel(const int* __restrict__ cnt, float* __restrict__ dinv, int n) {
  int i = blockIdx.x * blockDim.x + threadIdx.x;
  if (i >= n) return;
  dinv[i] = rsqrtf((float)(cnt[i] + 1));
}

// ---------------- MFMA GEMM 1: hx = x @ W1 ----------------

template<class T>
__global__ __launch_bounds__(256) void mfma_gemm1(const void* __restrict__ x,
                                                  const void* __restrict__ W1,
                                                  u16* __restrict__ hx,
                                                  const int* __restrict__ flags) {
  if (flags[0] != IsF32<T>::v) return;
  constexpr int PA = IsF32<T>::v ? 2 : 1;
  __shared__ __align__(16) u16 As[PA][128][40];
  __shared__ __align__(16) u16 Bs[128][40];
  const int t = threadIdx.x;
  const int rowBase = blockIdx.y * 128;
  const int colBase = blockIdx.x * 128;
  const int lane = t & 63;
  const int wid = t >> 6;
  const int wm = (wid >> 1) * 64;
  const int wn = (wid & 1) * 64;
  const int fr = lane & 15;
  const int kc = lane >> 4;

  f32x4 acc[4][4] = {};

  for (int kt = 0; kt < IN_CH / 32; ++kt) {
    {
      int row = t >> 1;
      int c0 = (t & 1) * 16;
      int r = rowBase + row; if (r >= N_NODES) r = N_NODES - 1;
      size_t gb = (size_t)r * IN_CH + kt * 32 + c0;
      if (IsF32<T>::v) {
        u16 th[16], tl[16];
        const float* xp = (const float*)x + gb;
#pragma unroll
        for (int q = 0; q < 4; ++q) {
          float4 v = *(const float4*)(xp + 4 * q);
          float vv[4] = {v.x, v.y, v.z, v.w};
#pragma unroll
          for (int j = 0; j < 4; ++j) {
            u16 hb = f2b(vv[j]);
            th[4 * q + j] = hb;
            tl[4 * q + j] = f2b(vv[j] - b2f(hb));
          }
        }
        *(uint4*)&As[0][row][c0]     = *(uint4*)&th[0];
        *(uint4*)&As[0][row][c0 + 8] = *(uint4*)&th[8];
        *(uint4*)&As[1][row][c0]     = *(uint4*)&tl[0];
        *(uint4*)&As[1][row][c0 + 8] = *(uint4*)&tl[8];
      } else {
        const u16* xp = (const u16*)x + gb;
        *(uint4*)&As[0][row][c0]     = *(const uint4*)(xp);
        *(uint4*)&As[0][row][c0 + 8] = *(const uint4*)(xp + 8);
      }
    }
    if (IsF32<T>::v) {
      for (int i = t; i < 1024; i += 256) {
        int k = i >> 5, g = i & 31;
        const float* p = (const float*)W1 + ((size_t)(kt * 32 + k) * HID_CH + colBase + g * 4);
        float4 v = *(const float4*)p;
        float vv[4] = {v.x, v.y, v.z, v.w};
#pragma unroll
        for (int j = 0; j < 4; ++j) Bs[g * 4 + j][k] = f2b(vv[j]);
      }
    } else {
      for (int i = t; i < 512; i += 256) {
        int k = i >> 4, g = i & 15;
        uint4 v = *(const uint4*)((const u16*)W1 + ((size_t)(kt * 32 + k) * HID_CH + colBase + g * 8));
        const u16* pv = (const u16*)&v;
#pragma unroll
        for (int j = 0; j < 8; ++j) Bs[g * 8 + j][k] = pv[j];
      }
    }
    __syncthreads();
    bf16x8 b[4];
#pragma unroll
    for (int ni = 0; ni < 4; ++ni)
      b[ni] = *(const bf16x8*)&Bs[wn + ni * 16 + fr][kc * 8];
#pragma unroll
    for (int mi = 0; mi < 4; ++mi) {
      bf16x8 a0 = *(const bf16x8*)&As[0][wm + mi * 16 + fr][kc * 8];
#pragma unroll
      for (int ni = 0; ni < 4; ++ni)
        acc[mi][ni] = __builtin_amdgcn_mfma_f32_16x16x32_bf16(a0, b[ni], acc[mi][ni], 0, 0, 0);
      if (IsF32<T>::v) {
        bf16x8 a1 = *(const bf16x8*)&As[1][wm + mi * 16 + fr][kc * 8];
#pragma unroll
        for (int ni = 0; ni < 4; ++ni)
          acc[mi][ni] = __builtin_amdgcn_mfma_f32_16x16x32_bf16(a1, b[ni], acc[mi][ni], 0, 0, 0);
      }
    }
    __syncthreads();
  }
#pragma unroll
  for (int mi = 0; mi < 4; ++mi) {
#pragma unroll
    for (int ni = 0; ni < 4; ++ni) {
#pragma unroll
      for (int j = 0; j < 4; ++j) {
        int row = rowBase + wm + mi * 16 + kc * 4 + j;
        if (row < N_NODES) {
          int col = colBase + wn + ni * 16 + fr;
          hx[(size_t)row * HID_CH + col] = f2b(acc[mi][ni][j]);
        }
      }
    }
  }
}

// ---------------- MFMA GEMM 2: hml = h @ [Wmu | Wlv] ----------------

template<class T>
__global__ __launch_bounds__(256) void mfma_gemm2(const u16* __restrict__ h,
                                                  const void* __restrict__ Wmu,
                                                  const void* __restrict__ Wlv,
                                                  u16* __restrict__ hml,
                                                  const int* __restrict__ flags) {
  if (flags[0] != IsF32<T>::v) return;
  constexpr int PB = IsF32<T>::v ? 2 : 1;
  __shared__ __align__(16) u16 As[128][40];
  __shared__ __align__(16) u16 Bs[PB][128][40];
  const int t = threadIdx.x;
  const int rowBase = blockIdx.y * 128;
  const int lane = t & 63;
  const int wid = t >> 6;
  const int wm = (wid >> 1) * 64;
  const int wn = (wid & 1) * 64;
  const int fr = lane & 15;
  const int kc = lane >> 4;

  f32x4 acc[4][4] = {};

  for (int kt = 0; kt < HID_CH / 32; ++kt) {
    {
      int row = t >> 1;
      int c0 = (t & 1) * 16;
      int r = rowBase + row; if (r >= N_NODES) r = N_NODES - 1;
      const u16* hp = h + (size_t)r * HID_CH + kt * 32 + c0;
      *(uint4*)&As[row][c0]     = *(const uint4*)(hp);
      *(uint4*)&As[row][c0 + 8] = *(const uint4*)(hp + 8);
    }
    for (int i = t; i < 4096; i += 256) {
      int k = i >> 7, n = i & 127;
      const void* W = (n < 64) ? Wmu : Wlv;
      size_t idx = (size_t)(kt * 32 + k) * 64 + (n & 63);
      if (IsF32<T>::v) {
        float v = ((const float*)W)[idx];
        u16 hb = f2b(v);
        Bs[0][n][k] = hb;
        Bs[1][n][k] = f2b(v - b2f(hb));
      } else {
        Bs[0][n][k] = ((const u16*)W)[idx];
      }
    }
    __syncthreads();
    bf16x8 a[4];
#pragma unroll
    for (int mi = 0; mi < 4; ++mi)
      a[mi] = *(const bf16x8*)&As[wm + mi * 16 + fr][kc * 8];
#pragma unroll
    for (int ni = 0; ni < 4; ++ni) {
      bf16x8 b0 = *(const bf16x8*)&Bs[0][wn + ni * 16 + fr][kc * 8];
#pragma unroll
      for (int mi = 0; mi < 4; ++mi)
        acc[mi][ni] = __builtin_amdgcn_mfma_f32_16x16x32_bf16(a[mi], b0, acc[mi][ni], 0, 0, 0);
      if (IsF32<T>::v) {
        bf16x8 b1 = *(const bf16x8*)&Bs[1][wn + ni * 16 + fr][kc * 8];
#pragma unroll
        for (int mi = 0; mi < 4; ++mi)
          acc[mi][ni] = __builtin_amdgcn_mfma_f32_16x16x32_bf16(a[mi], b1, acc[mi][ni], 0, 0, 0);
      }
    }
    __syncthreads();
  }
#pragma unroll
  for (int mi = 0; mi < 4; ++mi) {
#pragma unroll
    for (int ni = 0; ni < 4; ++ni) {
#pragma unroll
      for (int j = 0; j < 4; ++j) {
        int row = rowBase + wm + mi * 16 + kc * 4 + j;
        if (row < N_NODES) {
          int col = wn + ni * 16 + fr;
          hml[(size_t)row * 128 + col] = f2b(acc[mi][ni][j]);
        }
      }
    }
  }
}

// ---------------- aggregation 1 (256 ch) + bias + relu -> h ----------------
// one wave per node; lane owns channels [4*lane, 4*lane+4); edge loop unrolled
// x8 with uint2 (8B) vector row loads so 8 gathers are in flight per wave.
// Accumulation order per lane is sequential in j (bitwise == old version).

template<class T>
__global__ __launch_bounds__(256) void agg1_kernel(const u16* __restrict__ hx,
                                                   const int* __restrict__ cnt,
                                                   const int* __restrict__ offs,
                                                   const int* __restrict__ adj,
                                                   const float* __restrict__ dinv,
                                                   const void* __restrict__ b1,
                                                   u16* __restrict__ h,
                                                   const int* __restrict__ flags) {
  if (flags[0] != IsF32<T>::v) return;
  int d = blockIdx.x * 4 + (threadIdx.x >> 6);
  if (d >= N_NODES) return;
  int lane = threadIdx.x & 63;
  const u16* base = hx + (size_t)lane * 4;  // 8B-aligned per lane
  float a0 = 0.f, a1 = 0.f, a2 = 0.f, a3 = 0.f;
  int n = cnt[d];
  float dv = dinv[d];
  const int* ent = adj + offs[d];
  int j = 0;
  for (; j + 8 <= n; j += 8) {
    int s[8]; float w[8]; uint2 v[8];
#pragma unroll
    for (int u = 0; u < 8; ++u) s[u] = ent[j + u];
#pragma unroll
    for (int u = 0; u < 8; ++u) w[u] = dv * dinv[s[u]];
#pragma unroll
    for (int u = 0; u < 8; ++u)
      v[u] = *(const uint2*)(base + (size_t)s[u] * HID_CH);
#pragma unroll
    for (int u = 0; u < 8; ++u) {
      a0 += w[u] * b2f((u16)(v[u].x & 0xffff));
      a1 += w[u] * b2f((u16)(v[u].x >> 16));
      a2 += w[u] * b2f((u16)(v[u].y & 0xffff));
      a3 += w[u] * b2f((u16)(v[u].y >> 16));
    }
  }
  for (; j < n; ++j) {
    int s = ent[j];
    float w = dv * dinv[s];
    uint2 v = *(const uint2*)(base + (size_t)s * HID_CH);
    a0 += w * b2f((u16)(v.x & 0xffff));
    a1 += w * b2f((u16)(v.x >> 16));
    a2 += w * b2f((u16)(v.y & 0xffff));
    a3 += w * b2f((u16)(v.y >> 16));
  }
  {  // self loop
    float w = dv * dv;
    uint2 v = *(const uint2*)(base + (size_t)d * HID_CH);
    a0 += w * b2f((u16)(v.x & 0xffff));
    a1 += w * b2f((u16)(v.x >> 16));
    a2 += w * b2f((u16)(v.y & 0xffff));
    a3 += w * b2f((u16)(v.y >> 16));
  }
  int c = lane * 4;
  a0 = fmaxf(a0 + ldv<T>(b1, c), 0.f);
  a1 = fmaxf(a1 + ldv<T>(b1, c + 1), 0.f);
  a2 = fmaxf(a2 + ldv<T>(b1, c + 2), 0.f);
  a3 = fmaxf(a3 + ldv<T>(b1, c + 3), 0.f);
  u16* q = h + (size_t)d * HID_CH + c;
  q[0] = f2b(a0); q[1] = f2b(a1); q[2] = f2b(a2); q[3] = f2b(a3);
}

// ---------------- aggregation 2 (128 ch) + bias + reparam ----------------
// lane owns channel-pair 2*lane of the 128-wide [mu|lv] row (uint load);
// lanes 0..31 accumulate mu channels, 32..63 the matching lv channels.
// One shfl pairs them for z. Edge loop unrolled x8.

template<class T>
__global__ __launch_bounds__(256) void agg2_kernel(const u16* __restrict__ hml,
                                                   const int* __restrict__ cnt,
                                                   const int* __restrict__ offs,
                                                   const int* __restrict__ adj,
                                                   const float* __restrict__ dinv,
                                                   const void* __restrict__ bmu,
                                                   const void* __restrict__ blv,
                                                   const void* __restrict__ eps,
                                                   void* __restrict__ mu_out,
                                                   void* __restrict__ lv_out,
                                                   u16* __restrict__ z,
                                                   const int* __restrict__ flags) {
  if (flags[0] != IsF32<T>::v) return;
  int d = blockIdx.x * 4 + (threadIdx.x >> 6);
  if (d >= N_NODES) return;
  int lane = threadIdx.x & 63;
  const u16* base = hml + (size_t)lane * 2;  // 4B-aligned per lane
  float a0 = 0.f, a1 = 0.f;
  int n = cnt[d];
  float dv = dinv[d];
  const int* ent = adj + offs[d];
  int j = 0;
  for (; j + 8 <= n; j += 8) {
    int s[8]; float w[8]; u32 v[8];
#pragma unroll
    for (int u = 0; u < 8; ++u) s[u] = ent[j + u];
#pragma unroll
    for (int u = 0; u < 8; ++u) w[u] = dv * dinv[s[u]];
#pragma unroll
    for (int u = 0; u < 8; ++u)
      v[u] = *(const u32*)(base + (size_t)s[u] * 128);
#pragma unroll
    for (int u = 0; u < 8; ++u) {
      a0 += w[u] * b2f((u16)(v[u] & 0xffff));
      a1 += w[u] * b2f((u16)(v[u] >> 16));
    }
  }
  for (; j < n; ++j) {
    int s = ent[j];
    float w = dv * dinv[s];
    u32 v = *(const u32*)(base + (size_t)s * 128);
    a0 += w * b2f((u16)(v & 0xffff));
    a1 += w * b2f((u16)(v >> 16));
  }
  {  // self loop
    float w = dv * dv;
    u32 v = *(const u32*)(base + (size_t)d * 128);
    a0 += w * b2f((u16)(v & 0xffff));
    a1 += w * b2f((u16)(v >> 16));
  }
  // lanes<32 hold mu ch {2*lane,2*lane+1}; lanes>=32 hold lv ch {2*(lane-32),..}
  float b0 = __shfl(a0, (lane & 31) + 32);
  float b1 = __shfl(a1, (lane & 31) + 32);
  int c0 = (lane & 31) * 2;
  if (lane < 32) {
    float m0 = a0 + ldv<T>(bmu, c0);
    float m1 = a1 + ldv<T>(bmu, c0 + 1);
    float l0 = b0 + ldv<T>(blv, c0);
    float l1 = b1 + ldv<T>(blv, c0 + 1);
    size_t o = (size_t)d * 64 + c0;
    stv<T>(mu_out, o, m0);
    stv<T>(mu_out, o + 1, m1);
    float z0 = m0 + ldv<T>(eps, o) * expf(0.5f * l0);
    float z1 = m1 + ldv<T>(eps, o + 1) * expf(0.5f * l1);
    z[o] = f2b(z0); z[o + 1] = f2b(z1);
  } else {
    float l0 = a0 + ldv<T>(blv, c0);
    float l1 = a1 + ldv<T>(blv, c0 + 1);
    size_t o = (size_t)d * 64 + c0;
    stv<T>(lv_out, o, l0);
    stv<T>(lv_out, o + 1, l1);
  }
}

// ---------------- final small GEMM: out = z @ Wc + bc ----------------

template<class T>
__global__ __launch_bounds__(256) void out_gemm(const u16* __restrict__ z,
                                                const void* __restrict__ Wc,
                                                const void* __restrict__ bc,
                                                void* __restrict__ out,
                                                const int* __restrict__ flags) {
  if (flags[0] != IsF32<T>::v) return;
  __shared__ float Wcs[64][65];
  __shared__ float zs[4][65];
  int t = threadIdx.x;
  for (int i = t; i < 4096; i += 256) Wcs[i >> 6][i & 63] = ldv<T>(Wc, i);
  int ln = t >> 6;
  int col = t & 63;
  int node = blockIdx.x * 4 + ln;
  zs[ln][col] = b2f(z[(size_t)node * 64 + col]);
  __syncthreads();
  float acc = ldv<T>(bc, col);
#pragma unroll
  for (int k = 0; k < 64; ++k) acc += zs[ln][k] * Wcs[k][col];
  stv<T>(out, (size_t)node * 64 + col, acc);
}

// ---------------- launch ----------------

extern "C" void kernel_launch(void* const* d_in, const int* in_sizes, int n_in,
                              void* d_out, int out_size, void* d_ws, size_t ws_size,
                              hipStream_t stream) {
  const void* x   = d_in[0];
  const int*  ei  = (const int*)d_in[1];
  const void* W1  = d_in[2];
  const void* b1  = d_in[3];
  const void* Wmu = d_in[4];
  const void* bmu = d_in[5];
  const void* Wlv = d_in[6];
  const void* blv = d_in[7];
  const void* Wc  = d_in[8];
  const void* bc  = d_in[9];
  const void* eps = d_in[10];
  int E = in_sizes[1] / 2;

  char* ws = (char*)d_ws;
  int*   flags  = (int*)(ws);                    // 64 B
  int*   cnt    = (int*)(ws + 1024);             // 400 KB
  int*   cursor = (int*)(ws + (512 << 10));      // 400 KB
  int*   offs   = (int*)(ws + (1 << 20));        // 400 KB
  float* dinv   = (float*)(ws + (1536 << 10));   // 400 KB
  int*   adj    = (int*)(ws + (2 << 20));        // 12.8 MB
  size_t hx_off = (2 << 20) + (size_t)CAP_E * 4;
  u16* hx  = (u16*)(ws + hx_off);                                  // 51.2 MB
  u16* h   = (u16*)(ws + hx_off + (size_t)N_NODES * HID_CH * 2);   // 51.2 MB
  u16* hml = hx;  // hx dead after agg1; reuse (25.6 MB)
  u16* z   = (u16*)(ws + hx_off + (size_t)N_NODES * 128 * 2);      // 12.8 MB

  hipMemsetAsync(ws, 0, 2 << 20, stream);

  detect_kernel<<<1, 256, 0, stream>>>((const u32*)x, ei, flags);
  count_kernel<<<(E + 255) / 256, 256, 0, stream>>>(ei, flags, cnt, E);
  scan_kernel<<<1, 256, 0, stream>>>(cnt, offs);
  fill_kernel<<<(E + 255) / 256, 256, 0, stream>>>(ei, flags, offs, cursor, adj, E);
  dinv_kernel<<<(N_NODES + 255) / 256, 256, 0, stream>>>(cnt, dinv, N_NODES);

  // hx = x @ W1  (MFMA)
  {
    dim3 g1(2, (N_NODES + 127) / 128);
    mfma_gemm1<TyBF ><<<g1, 256, 0, stream>>>(x, W1, hx, flags);
    mfma_gemm1<TyF32><<<g1, 256, 0, stream>>>(x, W1, hx, flags);
  }

  // h = relu(agg(hx) + b1)
  agg1_kernel<TyBF ><<<N_NODES / 4, 256, 0, stream>>>(hx, cnt, offs, adj, dinv, b1, h, flags);
  agg1_kernel<TyF32><<<N_NODES / 4, 256, 0, stream>>>(hx, cnt, offs, adj, dinv, b1, h, flags);

  // hml = h @ [Wmu | Wlv]  (MFMA)
  {
    dim3 g2(1, (N_NODES + 127) / 128);
    mfma_gemm2<TyBF ><<<g2, 256, 0, stream>>>(h, Wmu, Wlv, hml, flags);
    mfma_gemm2<TyF32><<<g2, 256, 0, stream>>>(h, Wmu, Wlv, hml, flags);
  }

  // mu, logvar, z
  {
    char* ob = (char*)d_out;
    size_t esz_bf = 2, esz_f32 = 4;
    void* mu_bf  = ob + (size_t)N_NODES * 64 * esz_bf;
    void* lv_bf  = ob + (size_t)N_NODES * 128 * esz_bf;
    void* mu_f32 = ob + (size_t)N_NODES * 64 * esz_f32;
    void* lv_f32 = ob + (size_t)N_NODES * 128 * esz_f32;
    agg2_kernel<TyBF ><<<N_NODES / 4, 256, 0, stream>>>(hml, cnt, offs, adj, dinv, bmu, blv,
                                                        eps, mu_bf, lv_bf, z, flags);
    agg2_kernel<TyF32><<<N_NODES / 4, 256, 0, stream>>>(hml, cnt, offs, adj, dinv, bmu, blv,
                                                        eps, mu_f32, lv_f32, z, flags);
  }

  // out = z @ Wc + bc
  out_gemm<TyBF ><<<N_NODES / 4, 256, 0, stream>>>(z, Wc, bc, d_out, flags);
  out_gemm<TyF32><<<N_NODES / 4, 256, 0, stream>>>(z, Wc, bc, d_out, flags);
}

// Round 4
// 1389.720 us; speedup vs baseline: 1.5879x; 1.0083x over previous
//
#include <hip/hip_runtime.h>

typedef unsigned short u16;
typedef unsigned int u32;

#define N_NODES 100000
#define IN_CH 512
#define HID_CH 256
#define CAP_E 3200000

typedef short bf16x8 __attribute__((ext_vector_type(8)));
typedef float f32x4 __attribute__((ext_vector_type(4)));

__device__ __forceinline__ float b2f(u16 u) {
  union { u32 i; float f; } v; v.i = ((u32)u) << 16; return v.f;
}
__device__ __forceinline__ u16 f2b(float f) {
  union { float f; u32 i; } v; v.f = f;
  u32 r = v.i + 0x7fffu + ((v.i >> 16) & 1u);
  return (u16)(r >> 16);
}

struct TyBF {}; struct TyF32 {};
template<class T> struct IsF32;
template<> struct IsF32<TyBF>  { static constexpr int v = 0; };
template<> struct IsF32<TyF32> { static constexpr int v = 1; };

template<class T> __device__ __forceinline__ float ldv(const void* p, size_t i);
template<> __device__ __forceinline__ float ldv<TyBF>(const void* p, size_t i) {
  return b2f(((const u16*)p)[i]);
}
template<> __device__ __forceinline__ float ldv<TyF32>(const void* p, size_t i) {
  return ((const float*)p)[i];
}
template<class T> __device__ __forceinline__ void stv(void* p, size_t i, float v);
template<> __device__ __forceinline__ void stv<TyBF>(void* p, size_t i, float v) {
  ((u16*)p)[i] = f2b(v);
}
template<> __device__ __forceinline__ void stv<TyF32>(void* p, size_t i, float v) {
  ((float*)p)[i] = v;
}

// ---------------- runtime dtype probes ----------------

__global__ void detect_kernel(const u32* __restrict__ xw, const int* __restrict__ ei,
                              int* __restrict__ flags) {
  __shared__ int c1, c2;
  int t = threadIdx.x;  // 256
  if (t == 0) { c1 = 0; c2 = 0; }
  __syncthreads();
  u32 w = xw[t];
  int e = (w >> 7) & 0xFF;
  if (e >= 110 && e <= 135) atomicAdd(&c1, 1);
  if (ei[2 * t + 1] != 0) atomicAdd(&c2, 1);
  __syncthreads();
  if (t == 0) {
    flags[0] = (c1 < 154) ? 1 : 0;
    flags[1] = (c2 > 0) ? 1 : 0;
  }
}

// ---------------- graph build (CSR) ----------------

__global__ void count_kernel(const int* __restrict__ ei, const int* __restrict__ flags,
                             int* __restrict__ cnt, int E) {
  int e = blockIdx.x * blockDim.x + threadIdx.x;
  if (e >= E) return;
  int s, d;
  if (flags[1]) { s = ei[e]; d = ei[E + e]; }
  else          { s = ei[2 * e]; d = ei[2 * (E + e)]; }
  if ((u32)s >= N_NODES || (u32)d >= N_NODES) return;
  atomicAdd(&cnt[d], 1);
}

__global__ __launch_bounds__(256) void scan_kernel(const int* __restrict__ cnt,
                                                   int* __restrict__ offs) {
  __shared__ int sums[256];
  __shared__ int carry;
  int t = threadIdx.x;
  if (t == 0) carry = 0;
  __syncthreads();
  const int CHUNK = 256 * 16;
  for (int base = 0; base < N_NODES; base += CHUNK) {
    int lo = base + t * 16;
    int v[16];
    int sum = 0;
#pragma unroll
    for (int j = 0; j < 16; ++j) {
      int i = lo + j;
      v[j] = (i < N_NODES) ? cnt[i] : 0;
      sum += v[j];
    }
    sums[t] = sum;
    __syncthreads();
    for (int ds = 1; ds < 256; ds <<= 1) {
      int add = (t >= ds) ? sums[t - ds] : 0;
      __syncthreads();
      sums[t] += add;
      __syncthreads();
    }
    int excl = carry + sums[t] - sum;
#pragma unroll
    for (int j = 0; j < 16; ++j) {
      int i = lo + j;
      if (i < N_NODES) offs[i] = excl;
      excl += v[j];
    }
    __syncthreads();
    if (t == 255) carry += sums[255];
    __syncthreads();
  }
}

__global__ void fill_kernel(const int* __restrict__ ei, const int* __restrict__ flags,
                            const int* __restrict__ offs, int* __restrict__ cursor,
                            int* __restrict__ adj, int E) {
  int e = blockIdx.x * blockDim.x + threadIdx.x;
  if (e >= E) return;
  int s, d;
  if (flags[1]) { s = ei[e]; d = ei[E + e]; }
  else          { s = ei[2 * e]; d = ei[2 * (E + e)]; }
  if ((u32)s >= N_NODES || (u32)d >= N_NODES) return;
  int pos = atomicAdd(&cursor[d], 1);
  adj[offs[d] + pos] = s;
}

__global__ void dinv_kernel(const int* __restrict__ cnt, float* __restrict__ dinv, int n) {
  int i = blockIdx.x * blockDim.x + threadIdx.x;
  if (i >= n) return;
  dinv[i] = rsqrtf((float)(cnt[i] + 1));
}

// ---------------- MFMA GEMM 1: hx = x @ W1 ----------------

template<class T>
__global__ __launch_bounds__(256) void mfma_gemm1(const void* __restrict__ x,
                                                  const void* __restrict__ W1,
                                                  u16* __restrict__ hx,
                                                  const int* __restrict__ flags) {
  if (flags[0] != IsF32<T>::v) return;
  constexpr int PA = IsF32<T>::v ? 2 : 1;
  __shared__ __align__(16) u16 As[PA][128][40];
  __shared__ __align__(16) u16 Bs[128][40];
  const int t = threadIdx.x;
  const int rowBase = blockIdx.y * 128;
  const int colBase = blockIdx.x * 128;
  const int lane = t & 63;
  const int wid = t >> 6;
  const int wm = (wid >> 1) * 64;
  const int wn = (wid & 1) * 64;
  const int fr = lane & 15;
  const int kc = lane >> 4;

  f32x4 acc[4][4] = {};

  for (int kt = 0; kt < IN_CH / 32; ++kt) {
    {
      int row = t >> 1;
      int c0 = (t & 1) * 16;
      int r = rowBase + row; if (r >= N_NODES) r = N_NODES - 1;
      size_t gb = (size_t)r * IN_CH + kt * 32 + c0;
      if (IsF32<T>::v) {
        u16 th[16], tl[16];
        const float* xp = (const float*)x + gb;
#pragma unroll
        for (int q = 0; q < 4; ++q) {
          float4 v = *(const float4*)(xp + 4 * q);
          float vv[4] = {v.x, v.y, v.z, v.w};
#pragma unroll
          for (int j = 0; j < 4; ++j) {
            u16 hb = f2b(vv[j]);
            th[4 * q + j] = hb;
            tl[4 * q + j] = f2b(vv[j] - b2f(hb));
          }
        }
        *(uint4*)&As[0][row][c0]     = *(uint4*)&th[0];
        *(uint4*)&As[0][row][c0 + 8] = *(uint4*)&th[8];
        *(uint4*)&As[1][row][c0]     = *(uint4*)&tl[0];
        *(uint4*)&As[1][row][c0 + 8] = *(uint4*)&tl[8];
      } else {
        const u16* xp = (const u16*)x + gb;
        *(uint4*)&As[0][row][c0]     = *(const uint4*)(xp);
        *(uint4*)&As[0][row][c0 + 8] = *(const uint4*)(xp + 8);
      }
    }
    if (IsF32<T>::v) {
      for (int i = t; i < 1024; i += 256) {
        int k = i >> 5, g = i & 31;
        const float* p = (const float*)W1 + ((size_t)(kt * 32 + k) * HID_CH + colBase + g * 4);
        float4 v = *(const float4*)p;
        float vv[4] = {v.x, v.y, v.z, v.w};
#pragma unroll
        for (int j = 0; j < 4; ++j) Bs[g * 4 + j][k] = f2b(vv[j]);
      }
    } else {
      for (int i = t; i < 512; i += 256) {
        int k = i >> 4, g = i & 15;
        uint4 v = *(const uint4*)((const u16*)W1 + ((size_t)(kt * 32 + k) * HID_CH + colBase + g * 8));
        const u16* pv = (const u16*)&v;
#pragma unroll
        for (int j = 0; j < 8; ++j) Bs[g * 8 + j][k] = pv[j];
      }
    }
    __syncthreads();
    bf16x8 b[4];
#pragma unroll
    for (int ni = 0; ni < 4; ++ni)
      b[ni] = *(const bf16x8*)&Bs[wn + ni * 16 + fr][kc * 8];
#pragma unroll
    for (int mi = 0; mi < 4; ++mi) {
      bf16x8 a0 = *(const bf16x8*)&As[0][wm + mi * 16 + fr][kc * 8];
#pragma unroll
      for (int ni = 0; ni < 4; ++ni)
        acc[mi][ni] = __builtin_amdgcn_mfma_f32_16x16x32_bf16(a0, b[ni], acc[mi][ni], 0, 0, 0);
      if (IsF32<T>::v) {
        bf16x8 a1 = *(const bf16x8*)&As[1][wm + mi * 16 + fr][kc * 8];
#pragma unroll
        for (int ni = 0; ni < 4; ++ni)
          acc[mi][ni] = __builtin_amdgcn_mfma_f32_16x16x32_bf16(a1, b[ni], acc[mi][ni], 0, 0, 0);
      }
    }
    __syncthreads();
  }
#pragma unroll
  for (int mi = 0; mi < 4; ++mi) {
#pragma unroll
    for (int ni = 0; ni < 4; ++ni) {
#pragma unroll
      for (int j = 0; j < 4; ++j) {
        int row = rowBase + wm + mi * 16 + kc * 4 + j;
        if (row < N_NODES) {
          int col = colBase + wn + ni * 16 + fr;
          hx[(size_t)row * HID_CH + col] = f2b(acc[mi][ni][j]);
        }
      }
    }
  }
}

// ---------------- MFMA GEMM 2: hml = h @ [Wmu | Wlv] ----------------

template<class T>
__global__ __launch_bounds__(256) void mfma_gemm2(const u16* __restrict__ h,
                                                  const void* __restrict__ Wmu,
                                                  const void* __restrict__ Wlv,
                                                  u16* __restrict__ hml,
                                                  const int* __restrict__ flags) {
  if (flags[0] != IsF32<T>::v) return;
  constexpr int PB = IsF32<T>::v ? 2 : 1;
  __shared__ __align__(16) u16 As[128][40];
  __shared__ __align__(16) u16 Bs[PB][128][40];
  const int t = threadIdx.x;
  const int rowBase = blockIdx.y * 128;
  const int lane = t & 63;
  const int wid = t >> 6;
  const int wm = (wid >> 1) * 64;
  const int wn = (wid & 1) * 64;
  const int fr = lane & 15;
  const int kc = lane >> 4;

  f32x4 acc[4][4] = {};

  for (int kt = 0; kt < HID_CH / 32; ++kt) {
    {
      int row = t >> 1;
      int c0 = (t & 1) * 16;
      int r = rowBase + row; if (r >= N_NODES) r = N_NODES - 1;
      const u16* hp = h + (size_t)r * HID_CH + kt * 32 + c0;
      *(uint4*)&As[row][c0]     = *(const uint4*)(hp);
      *(uint4*)&As[row][c0 + 8] = *(const uint4*)(hp + 8);
    }
    for (int i = t; i < 4096; i += 256) {
      int k = i >> 7, n = i & 127;
      const void* W = (n < 64) ? Wmu : Wlv;
      size_t idx = (size_t)(kt * 32 + k) * 64 + (n & 63);
      if (IsF32<T>::v) {
        float v = ((const float*)W)[idx];
        u16 hb = f2b(v);
        Bs[0][n][k] = hb;
        Bs[1][n][k] = f2b(v - b2f(hb));
      } else {
        Bs[0][n][k] = ((const u16*)W)[idx];
      }
    }
    __syncthreads();
    bf16x8 a[4];
#pragma unroll
    for (int mi = 0; mi < 4; ++mi)
      a[mi] = *(const bf16x8*)&As[wm + mi * 16 + fr][kc * 8];
#pragma unroll
    for (int ni = 0; ni < 4; ++ni) {
      bf16x8 b0 = *(const bf16x8*)&Bs[0][wn + ni * 16 + fr][kc * 8];
#pragma unroll
      for (int mi = 0; mi < 4; ++mi)
        acc[mi][ni] = __builtin_amdgcn_mfma_f32_16x16x32_bf16(a[mi], b0, acc[mi][ni], 0, 0, 0);
      if (IsF32<T>::v) {
        bf16x8 b1 = *(const bf16x8*)&Bs[1][wn + ni * 16 + fr][kc * 8];
#pragma unroll
        for (int mi = 0; mi < 4; ++mi)
          acc[mi][ni] = __builtin_amdgcn_mfma_f32_16x16x32_bf16(a[mi], b1, acc[mi][ni], 0, 0, 0);
      }
    }
    __syncthreads();
  }
#pragma unroll
  for (int mi = 0; mi < 4; ++mi) {
#pragma unroll
    for (int ni = 0; ni < 4; ++ni) {
#pragma unroll
      for (int j = 0; j < 4; ++j) {
        int row = rowBase + wm + mi * 16 + kc * 4 + j;
        if (row < N_NODES) {
          int col = wn + ni * 16 + fr;
          hml[(size_t)row * 128 + col] = f2b(acc[mi][ni][j]);
        }
      }
    }
  }
}

// ---------------- aggregation 1 (256 ch) + bias + relu -> h ----------------
// 2 nodes per wave: half-wave (32 lanes) per node, lane owns 8 channels and
// gathers a full uint4 (16B) per edge -> one dwordx4/lane covers the 512B row.
// Unroll x8 keeps 8KB/wave in flight. Per-channel j-order unchanged (bitwise
// identical numerics vs previous rounds).

template<class T>
__global__ __launch_bounds__(256) void agg1_kernel(const u16* __restrict__ hx,
                                                   const int* __restrict__ cnt,
                                                   const int* __restrict__ offs,
                                                   const int* __restrict__ adj,
                                                   const float* __restrict__ dinv,
                                                   const void* __restrict__ b1,
                                                   u16* __restrict__ h,
                                                   const int* __restrict__ flags) {
  if (flags[0] != IsF32<T>::v) return;
  int d = blockIdx.x * 8 + (threadIdx.x >> 5);
  if (d >= N_NODES) return;
  int sub = threadIdx.x & 31;
  const u16* base = hx + sub * 8;  // 16B-aligned per lane
  float a[8] = {};
  int n = cnt[d];
  float dv = dinv[d];
  const int* ent = adj + offs[d];
  int j = 0;
  for (; j + 8 <= n; j += 8) {
    int s[8]; float w[8]; uint4 v[8];
#pragma unroll
    for (int u = 0; u < 8; ++u) s[u] = ent[j + u];
#pragma unroll
    for (int u = 0; u < 8; ++u) w[u] = dv * dinv[s[u]];
#pragma unroll
    for (int u = 0; u < 8; ++u)
      v[u] = *(const uint4*)(base + (size_t)s[u] * HID_CH);
#pragma unroll
    for (int u = 0; u < 8; ++u) {
      a[0] += w[u] * b2f((u16)(v[u].x & 0xffff));
      a[1] += w[u] * b2f((u16)(v[u].x >> 16));
      a[2] += w[u] * b2f((u16)(v[u].y & 0xffff));
      a[3] += w[u] * b2f((u16)(v[u].y >> 16));
      a[4] += w[u] * b2f((u16)(v[u].z & 0xffff));
      a[5] += w[u] * b2f((u16)(v[u].z >> 16));
      a[6] += w[u] * b2f((u16)(v[u].w & 0xffff));
      a[7] += w[u] * b2f((u16)(v[u].w >> 16));
    }
  }
  for (; j < n; ++j) {
    int s = ent[j];
    float w = dv * dinv[s];
    uint4 v = *(const uint4*)(base + (size_t)s * HID_CH);
    a[0] += w * b2f((u16)(v.x & 0xffff));
    a[1] += w * b2f((u16)(v.x >> 16));
    a[2] += w * b2f((u16)(v.y & 0xffff));
    a[3] += w * b2f((u16)(v.y >> 16));
    a[4] += w * b2f((u16)(v.z & 0xffff));
    a[5] += w * b2f((u16)(v.z >> 16));
    a[6] += w * b2f((u16)(v.w & 0xffff));
    a[7] += w * b2f((u16)(v.w >> 16));
  }
  {  // self loop
    float w = dv * dv;
    uint4 v = *(const uint4*)(base + (size_t)d * HID_CH);
    a[0] += w * b2f((u16)(v.x & 0xffff));
    a[1] += w * b2f((u16)(v.x >> 16));
    a[2] += w * b2f((u16)(v.y & 0xffff));
    a[3] += w * b2f((u16)(v.y >> 16));
    a[4] += w * b2f((u16)(v.z & 0xffff));
    a[5] += w * b2f((u16)(v.z >> 16));
    a[6] += w * b2f((u16)(v.w & 0xffff));
    a[7] += w * b2f((u16)(v.w >> 16));
  }
  int c = sub * 8;
  u16 o16[8];
#pragma unroll
  for (int k = 0; k < 8; ++k)
    o16[k] = f2b(fmaxf(a[k] + ldv<T>(b1, c + k), 0.f));
  *(uint4*)(h + (size_t)d * HID_CH + c) = *(uint4*)&o16[0];
}

// ---------------- aggregation 2 (128 ch) + bias + reparam ----------------
// 2 nodes per wave: half-wave per node, lane owns 4 channels (uint2, 8B).
// sub<16 accumulate mu channels [4*sub,..), sub>=16 lv channels. One shfl
// within the half-wave pairs mu/lv for z.

template<class T>
__global__ __launch_bounds__(256) void agg2_kernel(const u16* __restrict__ hml,
                                                   const int* __restrict__ cnt,
                                                   const int* __restrict__ offs,
                                                   const int* __restrict__ adj,
                                                   const float* __restrict__ dinv,
                                                   const void* __restrict__ bmu,
                                                   const void* __restrict__ blv,
                                                   const void* __restrict__ eps,
                                                   void* __restrict__ mu_out,
                                                   void* __restrict__ lv_out,
                                                   u16* __restrict__ z,
                                                   const int* __restrict__ flags) {
  if (flags[0] != IsF32<T>::v) return;
  int d = blockIdx.x * 8 + (threadIdx.x >> 5);
  if (d >= N_NODES) return;
  int sub = threadIdx.x & 31;
  const u16* base = hml + sub * 4;  // 8B-aligned per lane
  float a[4] = {};
  int n = cnt[d];
  float dv = dinv[d];
  const int* ent = adj + offs[d];
  int j = 0;
  for (; j + 8 <= n; j += 8) {
    int s[8]; float w[8]; uint2 v[8];
#pragma unroll
    for (int u = 0; u < 8; ++u) s[u] = ent[j + u];
#pragma unroll
    for (int u = 0; u < 8; ++u) w[u] = dv * dinv[s[u]];
#pragma unroll
    for (int u = 0; u < 8; ++u)
      v[u] = *(const uint2*)(base + (size_t)s[u] * 128);
#pragma unroll
    for (int u = 0; u < 8; ++u) {
      a[0] += w[u] * b2f((u16)(v[u].x & 0xffff));
      a[1] += w[u] * b2f((u16)(v[u].x >> 16));
      a[2] += w[u] * b2f((u16)(v[u].y & 0xffff));
      a[3] += w[u] * b2f((u16)(v[u].y >> 16));
    }
  }
  for (; j < n; ++j) {
    int s = ent[j];
    float w = dv * dinv[s];
    uint2 v = *(const uint2*)(base + (size_t)s * 128);
    a[0] += w * b2f((u16)(v.x & 0xffff));
    a[1] += w * b2f((u16)(v.x >> 16));
    a[2] += w * b2f((u16)(v.y & 0xffff));
    a[3] += w * b2f((u16)(v.y >> 16));
  }
  {  // self loop
    float w = dv * dv;
    uint2 v = *(const uint2*)(base + (size_t)d * 128);
    a[0] += w * b2f((u16)(v.x & 0xffff));
    a[1] += w * b2f((u16)(v.x >> 16));
    a[2] += w * b2f((u16)(v.y & 0xffff));
    a[3] += w * b2f((u16)(v.y >> 16));
  }
  // pair mu (sub<16) with lv (sub+16) inside the half-wave
  int lane = threadIdx.x & 63;
  int partner = (lane & 32) | (((lane & 31) + 16) & 31);
  float p0 = __shfl(a[0], partner);
  float p1 = __shfl(a[1], partner);
  float p2 = __shfl(a[2], partner);
  float p3 = __shfl(a[3], partner);
  if (sub < 16) {
    int c = sub * 4;
    float m[4] = {a[0], a[1], a[2], a[3]};
    float l[4] = {p0, p1, p2, p3};
    size_t o = (size_t)d * 64 + c;
    u16 z16[4];
#pragma unroll
    for (int k = 0; k < 4; ++k) {
      m[k] += ldv<T>(bmu, c + k);
      l[k] += ldv<T>(blv, c + k);
      stv<T>(mu_out, o + k, m[k]);
      z16[k] = f2b(m[k] + ldv<T>(eps, o + k) * expf(0.5f * l[k]));
    }
    *(uint2*)(z + o) = *(uint2*)&z16[0];
  } else {
    int c = (sub - 16) * 4;
    size_t o = (size_t)d * 64 + c;
#pragma unroll
    for (int k = 0; k < 4; ++k)
      stv<T>(lv_out, o + k, a[k] + ldv<T>(blv, c + k));
  }
}

// ---------------- final small GEMM: out = z @ Wc + bc ----------------

template<class T>
__global__ __launch_bounds__(256) void out_gemm(const u16* __restrict__ z,
                                                const void* __restrict__ Wc,
                                                const void* __restrict__ bc,
                                                void* __restrict__ out,
                                                const int* __restrict__ flags) {
  if (flags[0] != IsF32<T>::v) return;
  __shared__ float Wcs[64][65];
  __shared__ float zs[4][65];
  int t = threadIdx.x;
  for (int i = t; i < 4096; i += 256) Wcs[i >> 6][i & 63] = ldv<T>(Wc, i);
  int ln = t >> 6;
  int col = t & 63;
  int node = blockIdx.x * 4 + ln;
  zs[ln][col] = b2f(z[(size_t)node * 64 + col]);
  __syncthreads();
  float acc = ldv<T>(bc, col);
#pragma unroll
  for (int k = 0; k < 64; ++k) acc += zs[ln][k] * Wcs[k][col];
  stv<T>(out, (size_t)node * 64 + col, acc);
}

// ---------------- launch ----------------

extern "C" void kernel_launch(void* const* d_in, const int* in_sizes, int n_in,
                              void* d_out, int out_size, void* d_ws, size_t ws_size,
                              hipStream_t stream) {
  const void* x   = d_in[0];
  const int*  ei  = (const int*)d_in[1];
  const void* W1  = d_in[2];
  const void* b1  = d_in[3];
  const void* Wmu = d_in[4];
  const void* bmu = d_in[5];
  const void* Wlv = d_in[6];
  const void* blv = d_in[7];
  const void* Wc  = d_in[8];
  const void* bc  = d_in[9];
  const void* eps = d_in[10];
  int E = in_sizes[1] / 2;

  char* ws = (char*)d_ws;
  int*   flags  = (int*)(ws);                    // 64 B
  int*   cnt    = (int*)(ws + 1024);             // 400 KB
  int*   cursor = (int*)(ws + (512 << 10));      // 400 KB
  int*   offs   = (int*)(ws + (1 << 20));        // 400 KB
  float* dinv   = (float*)(ws + (1536 << 10));   // 400 KB
  int*   adj    = (int*)(ws + (2 << 20));        // 12.8 MB
  size_t hx_off = (2 << 20) + (size_t)CAP_E * 4;
  u16* hx  = (u16*)(ws + hx_off);                                  // 51.2 MB
  u16* h   = (u16*)(ws + hx_off + (size_t)N_NODES * HID_CH * 2);   // 51.2 MB
  u16* hml = hx;  // hx dead after agg1; reuse (25.6 MB)
  u16* z   = (u16*)(ws + hx_off + (size_t)N_NODES * 128 * 2);      // 12.8 MB

  hipMemsetAsync(ws, 0, 2 << 20, stream);

  detect_kernel<<<1, 256, 0, stream>>>((const u32*)x, ei, flags);
  count_kernel<<<(E + 255) / 256, 256, 0, stream>>>(ei, flags, cnt, E);
  scan_kernel<<<1, 256, 0, stream>>>(cnt, offs);
  fill_kernel<<<(E + 255) / 256, 256, 0, stream>>>(ei, flags, offs, cursor, adj, E);
  dinv_kernel<<<(N_NODES + 255) / 256, 256, 0, stream>>>(cnt, dinv, N_NODES);

  // hx = x @ W1  (MFMA)
  {
    dim3 g1(2, (N_NODES + 127) / 128);
    mfma_gemm1<TyBF ><<<g1, 256, 0, stream>>>(x, W1, hx, flags);
    mfma_gemm1<TyF32><<<g1, 256, 0, stream>>>(x, W1, hx, flags);
  }

  // h = relu(agg(hx) + b1)
  {
    int g = (N_NODES + 7) / 8;
    agg1_kernel<TyBF ><<<g, 256, 0, stream>>>(hx, cnt, offs, adj, dinv, b1, h, flags);
    agg1_kernel<TyF32><<<g, 256, 0, stream>>>(hx, cnt, offs, adj, dinv, b1, h, flags);
  }

  // hml = h @ [Wmu | Wlv]  (MFMA)
  {
    dim3 g2(1, (N_NODES + 127) / 128);
    mfma_gemm2<TyBF ><<<g2, 256, 0, stream>>>(h, Wmu, Wlv, hml, flags);
    mfma_gemm2<TyF32><<<g2, 256, 0, stream>>>(h, Wmu, Wlv, hml, flags);
  }

  // mu, logvar, z
  {
    char* ob = (char*)d_out;
    size_t esz_bf = 2, esz_f32 = 4;
    void* mu_bf  = ob + (size_t)N_NODES * 64 * esz_bf;
    void* lv_bf  = ob + (size_t)N_NODES * 128 * esz_bf;
    void* mu_f32 = ob + (size_t)N_NODES * 64 * esz_f32;
    void* lv_f32 = ob + (size_t)N_NODES * 128 * esz_f32;
    int g = (N_NODES + 7) / 8;
    agg2_kernel<TyBF ><<<g, 256, 0, stream>>>(hml, cnt, offs, adj, dinv, bmu, blv,
                                              eps, mu_bf, lv_bf, z, flags);
    agg2_kernel<TyF32><<<g, 256, 0, stream>>>(hml, cnt, offs, adj, dinv, bmu, blv,
                                              eps, mu_f32, lv_f32, z, flags);
  }

  // out = z @ Wc + bc
  out_gemm<TyBF ><<<N_NODES / 4, 256, 0, stream>>>(z, Wc, bc, d_out, flags);
  out_gemm<TyF32><<<N_NODES / 4, 256, 0, stream>>>(z, Wc, bc, d_out, flags);
}

// Round 5
// 1277.068 us; speedup vs baseline: 1.7279x; 1.0882x over previous
//
#include <hip/hip_runtime.h>

typedef unsigned short u16;
typedef unsigned int u32;

#define N_NODES 100000
#define IN_CH 512
#define HID_CH 256
#define CAP_E 3200000
#define SCAN_NB 391  // ceil(N_NODES/256)

typedef short bf16x8 __attribute__((ext_vector_type(8)));
typedef float f32x4 __attribute__((ext_vector_type(4)));

__device__ __forceinline__ float b2f(u16 u) {
  union { u32 i; float f; } v; v.i = ((u32)u) << 16; return v.f;
}
__device__ __forceinline__ u16 f2b(float f) {
  union { float f; u32 i; } v; v.f = f;
  u32 r = v.i + 0x7fffu + ((v.i >> 16) & 1u);
  return (u16)(r >> 16);
}

struct TyBF {}; struct TyF32 {};
template<class T> struct IsF32;
template<> struct IsF32<TyBF>  { static constexpr int v = 0; };
template<> struct IsF32<TyF32> { static constexpr int v = 1; };

template<class T> __device__ __forceinline__ float ldv(const void* p, size_t i);
template<> __device__ __forceinline__ float ldv<TyBF>(const void* p, size_t i) {
  return b2f(((const u16*)p)[i]);
}
template<> __device__ __forceinline__ float ldv<TyF32>(const void* p, size_t i) {
  return ((const float*)p)[i];
}
template<class T> __device__ __forceinline__ void stv(void* p, size_t i, float v);
template<> __device__ __forceinline__ void stv<TyBF>(void* p, size_t i, float v) {
  ((u16*)p)[i] = f2b(v);
}
template<> __device__ __forceinline__ void stv<TyF32>(void* p, size_t i, float v) {
  ((float*)p)[i] = v;
}

// ---------------- runtime dtype probes ----------------

__global__ void detect_kernel(const u32* __restrict__ xw, const int* __restrict__ ei,
                              int* __restrict__ flags) {
  __shared__ int c1, c2;
  int t = threadIdx.x;  // 256
  if (t == 0) { c1 = 0; c2 = 0; }
  __syncthreads();
  u32 w = xw[t];
  int e = (w >> 7) & 0xFF;
  if (e >= 110 && e <= 135) atomicAdd(&c1, 1);
  if (ei[2 * t + 1] != 0) atomicAdd(&c2, 1);
  __syncthreads();
  if (t == 0) {
    flags[0] = (c1 < 154) ? 1 : 0;
    flags[1] = (c2 > 0) ? 1 : 0;
  }
}

// ---------------- graph build (CSR) ----------------

__global__ void count_kernel(const int* __restrict__ ei, const int* __restrict__ flags,
                             int* __restrict__ cnt, int E) {
  int e = blockIdx.x * blockDim.x + threadIdx.x;
  if (e >= E) return;
  int s, d;
  if (flags[1]) { s = ei[e]; d = ei[E + e]; }
  else          { s = ei[2 * e]; d = ei[2 * (E + e)]; }
  if ((u32)s >= N_NODES || (u32)d >= N_NODES) return;
  atomicAdd(&cnt[d], 1);
}

// ---- parallel 3-phase exclusive scan of cnt -> offs ----

__global__ __launch_bounds__(256) void scan_blk(const int* __restrict__ cnt,
                                                int* __restrict__ offs,
                                                int* __restrict__ bsum) {
  __shared__ int s[256];
  int t = threadIdx.x;
  int i = blockIdx.x * 256 + t;
  int v = (i < N_NODES) ? cnt[i] : 0;
  s[t] = v;
  __syncthreads();
  for (int d = 1; d < 256; d <<= 1) {
    int add = (t >= d) ? s[t - d] : 0;
    __syncthreads();
    s[t] += add;
    __syncthreads();
  }
  if (i < N_NODES) offs[i] = s[t] - v;
  if (t == 255) bsum[blockIdx.x] = s[255];
}

__global__ __launch_bounds__(512) void scan_top(const int* __restrict__ bsum,
                                                int* __restrict__ bpre) {
  __shared__ int s[512];
  int t = threadIdx.x;
  int v = (t < SCAN_NB) ? bsum[t] : 0;
  s[t] = v;
  __syncthreads();
  for (int d = 1; d < 512; d <<= 1) {
    int add = (t >= d) ? s[t - d] : 0;
    __syncthreads();
    s[t] += add;
    __syncthreads();
  }
  if (t < SCAN_NB) bpre[t] = s[t] - v;
}

__global__ __launch_bounds__(256) void scan_add(int* __restrict__ offs,
                                                const int* __restrict__ bpre) {
  int i = blockIdx.x * 256 + threadIdx.x;
  if (i < N_NODES) offs[i] += bpre[blockIdx.x];
}

__global__ void fill_kernel(const int* __restrict__ ei, const int* __restrict__ flags,
                            const int* __restrict__ offs, int* __restrict__ cursor,
                            int* __restrict__ adj, int E) {
  int e = blockIdx.x * blockDim.x + threadIdx.x;
  if (e >= E) return;
  int s, d;
  if (flags[1]) { s = ei[e]; d = ei[E + e]; }
  else          { s = ei[2 * e]; d = ei[2 * (E + e)]; }
  if ((u32)s >= N_NODES || (u32)d >= N_NODES) return;
  int pos = atomicAdd(&cursor[d], 1);
  adj[offs[d] + pos] = s;
}

__global__ void dinv_kernel(const int* __restrict__ cnt, float* __restrict__ dinv, int n) {
  int i = blockIdx.x * blockDim.x + threadIdx.x;
  if (i >= n) return;
  dinv[i] = rsqrtf((float)(cnt[i] + 1));
}

// ---------------- MFMA GEMM 1: hx = x @ W1 ----------------
// BM=128 x BN=256 (full HID_CH) single pass: x staged/converted once.
// 8 waves (2m x 4n), each 64x64 = 4x4 frags of 16x16x32. BK=32.
// fp32 mode: A split into hi+lo bf16 planes; W1 rounded to bf16.

template<class T>
__global__ __launch_bounds__(512) void mfma_gemm1(const void* __restrict__ x,
                                                  const void* __restrict__ W1,
                                                  u16* __restrict__ hx,
                                                  const int* __restrict__ flags) {
  if (flags[0] != IsF32<T>::v) return;
  constexpr int PA = IsF32<T>::v ? 2 : 1;
  __shared__ __align__(16) u16 As[PA][128][40];
  __shared__ __align__(16) u16 Bs[256][40];
  const int t = threadIdx.x;
  const int rowBase = blockIdx.x * 128;
  const int lane = t & 63;
  const int wid = t >> 6;           // 0..7
  const int wm = (wid >> 2) * 64;   // 0,64
  const int wn = (wid & 3) * 64;    // 0,64,128,192
  const int fr = lane & 15;
  const int kc = lane >> 4;

  f32x4 acc[4][4] = {};

  for (int kt = 0; kt < IN_CH / 32; ++kt) {
    // ---- stage A tile (128 rows x 32 k): thread handles 8 floats ----
    {
      int row = t >> 2;
      int c0 = (t & 3) * 8;
      int r = rowBase + row; if (r >= N_NODES) r = N_NODES - 1;
      size_t gb = (size_t)r * IN_CH + kt * 32 + c0;
      if (IsF32<T>::v) {
        u16 th[8], tl[8];
        const float* xp = (const float*)x + gb;
#pragma unroll
        for (int q = 0; q < 2; ++q) {
          float4 v = *(const float4*)(xp + 4 * q);
          float vv[4] = {v.x, v.y, v.z, v.w};
#pragma unroll
          for (int j = 0; j < 4; ++j) {
            u16 hb = f2b(vv[j]);
            th[4 * q + j] = hb;
            tl[4 * q + j] = f2b(vv[j] - b2f(hb));
          }
        }
        *(uint4*)&As[0][row][c0] = *(uint4*)&th[0];
        *(uint4*)&As[1][row][c0] = *(uint4*)&tl[0];
      } else {
        const u16* xp = (const u16*)x + gb;
        *(uint4*)&As[0][row][c0] = *(const uint4*)(xp);
      }
    }
    // ---- stage B tile (32 k x 256 n) -> Bs[n][k] ----
    if (IsF32<T>::v) {
      for (int i = t; i < 2048; i += 512) {
        int k = i >> 6, g = i & 63;
        const float* p = (const float*)W1 + ((size_t)(kt * 32 + k) * HID_CH + g * 4);
        float4 v = *(const float4*)p;
        float vv[4] = {v.x, v.y, v.z, v.w};
#pragma unroll
        for (int j = 0; j < 4; ++j) Bs[g * 4 + j][k] = f2b(vv[j]);
      }
    } else {
      for (int i = t; i < 1024; i += 512) {
        int k = i >> 5, g = i & 31;
        uint4 v = *(const uint4*)((const u16*)W1 + ((size_t)(kt * 32 + k) * HID_CH + g * 8));
        const u16* pv = (const u16*)&v;
#pragma unroll
        for (int j = 0; j < 8; ++j) Bs[g * 8 + j][k] = pv[j];
      }
    }
    __syncthreads();
    // ---- fragments + MFMA ----
    bf16x8 b[4];
#pragma unroll
    for (int ni = 0; ni < 4; ++ni)
      b[ni] = *(const bf16x8*)&Bs[wn + ni * 16 + fr][kc * 8];
#pragma unroll
    for (int mi = 0; mi < 4; ++mi) {
      bf16x8 a0 = *(const bf16x8*)&As[0][wm + mi * 16 + fr][kc * 8];
#pragma unroll
      for (int ni = 0; ni < 4; ++ni)
        acc[mi][ni] = __builtin_amdgcn_mfma_f32_16x16x32_bf16(a0, b[ni], acc[mi][ni], 0, 0, 0);
      if (IsF32<T>::v) {
        bf16x8 a1 = *(const bf16x8*)&As[1][wm + mi * 16 + fr][kc * 8];
#pragma unroll
        for (int ni = 0; ni < 4; ++ni)
          acc[mi][ni] = __builtin_amdgcn_mfma_f32_16x16x32_bf16(a1, b[ni], acc[mi][ni], 0, 0, 0);
      }
    }
    __syncthreads();
  }
  // ---- epilogue: C/D layout col=lane&15, row=(lane>>4)*4+j ----
#pragma unroll
  for (int mi = 0; mi < 4; ++mi) {
#pragma unroll
    for (int ni = 0; ni < 4; ++ni) {
#pragma unroll
      for (int j = 0; j < 4; ++j) {
        int row = rowBase + wm + mi * 16 + kc * 4 + j;
        if (row < N_NODES) {
          int col = wn + ni * 16 + fr;
          hx[(size_t)row * HID_CH + col] = f2b(acc[mi][ni][j]);
        }
      }
    }
  }
}

// ---------------- MFMA GEMM 2: hml = h @ [Wmu | Wlv] ----------------

template<class T>
__global__ __launch_bounds__(256) void mfma_gemm2(const u16* __restrict__ h,
                                                  const void* __restrict__ Wmu,
                                                  const void* __restrict__ Wlv,
                                                  u16* __restrict__ hml,
                                                  const int* __restrict__ flags) {
  if (flags[0] != IsF32<T>::v) return;
  constexpr int PB = IsF32<T>::v ? 2 : 1;
  __shared__ __align__(16) u16 As[128][40];
  __shared__ __align__(16) u16 Bs[PB][128][40];
  const int t = threadIdx.x;
  const int rowBase = blockIdx.y * 128;
  const int lane = t & 63;
  const int wid = t >> 6;
  const int wm = (wid >> 1) * 64;
  const int wn = (wid & 1) * 64;
  const int fr = lane & 15;
  const int kc = lane >> 4;

  f32x4 acc[4][4] = {};

  for (int kt = 0; kt < HID_CH / 32; ++kt) {
    {
      int row = t >> 1;
      int c0 = (t & 1) * 16;
      int r = rowBase + row; if (r >= N_NODES) r = N_NODES - 1;
      const u16* hp = h + (size_t)r * HID_CH + kt * 32 + c0;
      *(uint4*)&As[row][c0]     = *(const uint4*)(hp);
      *(uint4*)&As[row][c0 + 8] = *(const uint4*)(hp + 8);
    }
    for (int i = t; i < 4096; i += 256) {
      int k = i >> 7, n = i & 127;
      const void* W = (n < 64) ? Wmu : Wlv;
      size_t idx = (size_t)(kt * 32 + k) * 64 + (n & 63);
      if (IsF32<T>::v) {
        float v = ((const float*)W)[idx];
        u16 hb = f2b(v);
        Bs[0][n][k] = hb;
        Bs[1][n][k] = f2b(v - b2f(hb));
      } else {
        Bs[0][n][k] = ((const u16*)W)[idx];
      }
    }
    __syncthreads();
    bf16x8 a[4];
#pragma unroll
    for (int mi = 0; mi < 4; ++mi)
      a[mi] = *(const bf16x8*)&As[wm + mi * 16 + fr][kc * 8];
#pragma unroll
    for (int ni = 0; ni < 4; ++ni) {
      bf16x8 b0 = *(const bf16x8*)&Bs[0][wn + ni * 16 + fr][kc * 8];
#pragma unroll
      for (int mi = 0; mi < 4; ++mi)
        acc[mi][ni] = __builtin_amdgcn_mfma_f32_16x16x32_bf16(a[mi], b0, acc[mi][ni], 0, 0, 0);
      if (IsF32<T>::v) {
        bf16x8 b1 = *(const bf16x8*)&Bs[1][wn + ni * 16 + fr][kc * 8];
#pragma unroll
        for (int mi = 0; mi < 4; ++mi)
          acc[mi][ni] = __builtin_amdgcn_mfma_f32_16x16x32_bf16(a[mi], b1, acc[mi][ni], 0, 0, 0);
      }
    }
    __syncthreads();
  }
#pragma unroll
  for (int mi = 0; mi < 4; ++mi) {
#pragma unroll
    for (int ni = 0; ni < 4; ++ni) {
#pragma unroll
      for (int j = 0; j < 4; ++j) {
        int row = rowBase + wm + mi * 16 + kc * 4 + j;
        if (row < N_NODES) {
          int col = wn + ni * 16 + fr;
          hml[(size_t)row * 128 + col] = f2b(acc[mi][ni][j]);
        }
      }
    }
  }
}

// ---------------- aggregation 1 (256 ch) + bias + relu -> h ----------------
// 2 nodes per wave: half-wave (32 lanes) per node, lane owns 8 channels,
// uint4 (16B) gather per edge, unroll x8. At the measured ~7.5 TB/s
// delivered random-gather ceiling (R3/R4 both plateau here).

template<class T>
__global__ __launch_bounds__(256) void agg1_kernel(const u16* __restrict__ hx,
                                                   const int* __restrict__ cnt,
                                                   const int* __restrict__ offs,
                                                   const int* __restrict__ adj,
                                                   const float* __restrict__ dinv,
                                                   const void* __restrict__ b1,
                                                   u16* __restrict__ h,
                                                   const int* __restrict__ flags) {
  if (flags[0] != IsF32<T>::v) return;
  int d = blockIdx.x * 8 + (threadIdx.x >> 5);
  if (d >= N_NODES) return;
  int sub = threadIdx.x & 31;
  const u16* base = hx + sub * 8;
  float a[8] = {};
  int n = cnt[d];
  float dv = dinv[d];
  const int* ent = adj + offs[d];
  int j = 0;
  for (; j + 8 <= n; j += 8) {
    int s[8]; float w[8]; uint4 v[8];
#pragma unroll
    for (int u = 0; u < 8; ++u) s[u] = ent[j + u];
#pragma unroll
    for (int u = 0; u < 8; ++u) w[u] = dv * dinv[s[u]];
#pragma unroll
    for (int u = 0; u < 8; ++u)
      v[u] = *(const uint4*)(base + (size_t)s[u] * HID_CH);
#pragma unroll
    for (int u = 0; u < 8; ++u) {
      a[0] += w[u] * b2f((u16)(v[u].x & 0xffff));
      a[1] += w[u] * b2f((u16)(v[u].x >> 16));
      a[2] += w[u] * b2f((u16)(v[u].y & 0xffff));
      a[3] += w[u] * b2f((u16)(v[u].y >> 16));
      a[4] += w[u] * b2f((u16)(v[u].z & 0xffff));
      a[5] += w[u] * b2f((u16)(v[u].z >> 16));
      a[6] += w[u] * b2f((u16)(v[u].w & 0xffff));
      a[7] += w[u] * b2f((u16)(v[u].w >> 16));
    }
  }
  for (; j < n; ++j) {
    int s = ent[j];
    float w = dv * dinv[s];
    uint4 v = *(const uint4*)(base + (size_t)s * HID_CH);
    a[0] += w * b2f((u16)(v.x & 0xffff));
    a[1] += w * b2f((u16)(v.x >> 16));
    a[2] += w * b2f((u16)(v.y & 0xffff));
    a[3] += w * b2f((u16)(v.y >> 16));
    a[4] += w * b2f((u16)(v.z & 0xffff));
    a[5] += w * b2f((u16)(v.z >> 16));
    a[6] += w * b2f((u16)(v.w & 0xffff));
    a[7] += w * b2f((u16)(v.w >> 16));
  }
  {  // self loop
    float w = dv * dv;
    uint4 v = *(const uint4*)(base + (size_t)d * HID_CH);
    a[0] += w * b2f((u16)(v.x & 0xffff));
    a[1] += w * b2f((u16)(v.x >> 16));
    a[2] += w * b2f((u16)(v.y & 0xffff));
    a[3] += w * b2f((u16)(v.y >> 16));
    a[4] += w * b2f((u16)(v.z & 0xffff));
    a[5] += w * b2f((u16)(v.z >> 16));
    a[6] += w * b2f((u16)(v.w & 0xffff));
    a[7] += w * b2f((u16)(v.w >> 16));
  }
  int c = sub * 8;
  u16 o16[8];
#pragma unroll
  for (int k = 0; k < 8; ++k)
    o16[k] = f2b(fmaxf(a[k] + ldv<T>(b1, c + k), 0.f));
  *(uint4*)(h + (size_t)d * HID_CH + c) = *(uint4*)&o16[0];
}

// ---------------- aggregation 2 (128 ch) + bias + reparam ----------------

template<class T>
__global__ __launch_bounds__(256) void agg2_kernel(const u16* __restrict__ hml,
                                                   const int* __restrict__ cnt,
                                                   const int* __restrict__ offs,
                                                   const int* __restrict__ adj,
                                                   const float* __restrict__ dinv,
                                                   const void* __restrict__ bmu,
                                                   const void* __restrict__ blv,
                                                   const void* __restrict__ eps,
                                                   void* __restrict__ mu_out,
                                                   void* __restrict__ lv_out,
                                                   u16* __restrict__ z,
                                                   const int* __restrict__ flags) {
  if (flags[0] != IsF32<T>::v) return;
  int d = blockIdx.x * 8 + (threadIdx.x >> 5);
  if (d >= N_NODES) return;
  int sub = threadIdx.x & 31;
  const u16* base = hml + sub * 4;
  float a[4] = {};
  int n = cnt[d];
  float dv = dinv[d];
  const int* ent = adj + offs[d];
  int j = 0;
  for (; j + 8 <= n; j += 8) {
    int s[8]; float w[8]; uint2 v[8];
#pragma unroll
    for (int u = 0; u < 8; ++u) s[u] = ent[j + u];
#pragma unroll
    for (int u = 0; u < 8; ++u) w[u] = dv * dinv[s[u]];
#pragma unroll
    for (int u = 0; u < 8; ++u)
      v[u] = *(const uint2*)(base + (size_t)s[u] * 128);
#pragma unroll
    for (int u = 0; u < 8; ++u) {
      a[0] += w[u] * b2f((u16)(v[u].x & 0xffff));
      a[1] += w[u] * b2f((u16)(v[u].x >> 16));
      a[2] += w[u] * b2f((u16)(v[u].y & 0xffff));
      a[3] += w[u] * b2f((u16)(v[u].y >> 16));
    }
  }
  for (; j < n; ++j) {
    int s = ent[j];
    float w = dv * dinv[s];
    uint2 v = *(const uint2*)(base + (size_t)s * 128);
    a[0] += w * b2f((u16)(v.x & 0xffff));
    a[1] += w * b2f((u16)(v.x >> 16));
    a[2] += w * b2f((u16)(v.y & 0xffff));
    a[3] += w * b2f((u16)(v.y >> 16));
  }
  {  // self loop
    float w = dv * dv;
    uint2 v = *(const uint2*)(base + (size_t)d * 128);
    a[0] += w * b2f((u16)(v.x & 0xffff));
    a[1] += w * b2f((u16)(v.x >> 16));
    a[2] += w * b2f((u16)(v.y & 0xffff));
    a[3] += w * b2f((u16)(v.y >> 16));
  }
  int lane = threadIdx.x & 63;
  int partner = (lane & 32) | (((lane & 31) + 16) & 31);
  float p0 = __shfl(a[0], partner);
  float p1 = __shfl(a[1], partner);
  float p2 = __shfl(a[2], partner);
  float p3 = __shfl(a[3], partner);
  if (sub < 16) {
    int c = sub * 4;
    float m[4] = {a[0], a[1], a[2], a[3]};
    float l[4] = {p0, p1, p2, p3};
    size_t o = (size_t)d * 64 + c;
    u16 z16[4];
#pragma unroll
    for (int k = 0; k < 4; ++k) {
      m[k] += ldv<T>(bmu, c + k);
      l[k] += ldv<T>(blv, c + k);
      stv<T>(mu_out, o + k, m[k]);
      z16[k] = f2b(m[k] + ldv<T>(eps, o + k) * expf(0.5f * l[k]));
    }
    *(uint2*)(z + o) = *(uint2*)&z16[0];
  } else {
    int c = (sub - 16) * 4;
    size_t o = (size_t)d * 64 + c;
#pragma unroll
    for (int k = 0; k < 4; ++k)
      stv<T>(lv_out, o + k, a[k] + ldv<T>(blv, c + k));
  }
}

// ---------------- final small GEMM: out = z @ Wc + bc ----------------

template<class T>
__global__ __launch_bounds__(256) void out_gemm(const u16* __restrict__ z,
                                                const void* __restrict__ Wc,
                                                const void* __restrict__ bc,
                                                void* __restrict__ out,
                                                const int* __restrict__ flags) {
  if (flags[0] != IsF32<T>::v) return;
  __shared__ float Wcs[64][65];
  __shared__ float zs[4][65];
  int t = threadIdx.x;
  for (int i = t; i < 4096; i += 256) Wcs[i >> 6][i & 63] = ldv<T>(Wc, i);
  int ln = t >> 6;
  int col = t & 63;
  int node = blockIdx.x * 4 + ln;
  zs[ln][col] = b2f(z[(size_t)node * 64 + col]);
  __syncthreads();
  float acc = ldv<T>(bc, col);
#pragma unroll
  for (int k = 0; k < 64; ++k) acc += zs[ln][k] * Wcs[k][col];
  stv<T>(out, (size_t)node * 64 + col, acc);
}

// ---------------- launch ----------------

extern "C" void kernel_launch(void* const* d_in, const int* in_sizes, int n_in,
                              void* d_out, int out_size, void* d_ws, size_t ws_size,
                              hipStream_t stream) {
  const void* x   = d_in[0];
  const int*  ei  = (const int*)d_in[1];
  const void* W1  = d_in[2];
  const void* b1  = d_in[3];
  const void* Wmu = d_in[4];
  const void* bmu = d_in[5];
  const void* Wlv = d_in[6];
  const void* blv = d_in[7];
  const void* Wc  = d_in[8];
  const void* bc  = d_in[9];
  const void* eps = d_in[10];
  int E = in_sizes[1] / 2;

  char* ws = (char*)d_ws;
  int*   flags  = (int*)(ws);                    // 64 B
  int*   cnt    = (int*)(ws + 1024);             // 400 KB
  int*   cursor = (int*)(ws + (512 << 10));      // 400 KB
  int*   offs   = (int*)(ws + (1 << 20));        // 400 KB
  float* dinv   = (float*)(ws + (1536 << 10));   // 400 KB (scan scratch first)
  int*   bsum   = (int*)(ws + (1536 << 10));     // 1.6 KB (dead before dinv)
  int*   bpre   = bsum + 512;
  int*   adj    = (int*)(ws + (2 << 20));        // 12.8 MB
  size_t hx_off = (2 << 20) + (size_t)CAP_E * 4;
  u16* hx  = (u16*)(ws + hx_off);                                  // 51.2 MB
  u16* h   = (u16*)(ws + hx_off + (size_t)N_NODES * HID_CH * 2);   // 51.2 MB
  u16* hml = hx;  // hx dead after agg1; reuse (25.6 MB)
  u16* z   = (u16*)(ws + hx_off + (size_t)N_NODES * 128 * 2);      // 12.8 MB

  hipMemsetAsync(ws, 0, 2 << 20, stream);

  detect_kernel<<<1, 256, 0, stream>>>((const u32*)x, ei, flags);
  count_kernel<<<(E + 255) / 256, 256, 0, stream>>>(ei, flags, cnt, E);
  scan_blk<<<SCAN_NB, 256, 0, stream>>>(cnt, offs, bsum);
  scan_top<<<1, 512, 0, stream>>>(bsum, bpre);
  scan_add<<<SCAN_NB, 256, 0, stream>>>(offs, bpre);
  fill_kernel<<<(E + 255) / 256, 256, 0, stream>>>(ei, flags, offs, cursor, adj, E);
  dinv_kernel<<<(N_NODES + 255) / 256, 256, 0, stream>>>(cnt, dinv, N_NODES);

  // hx = x @ W1  (MFMA, 128x256 tile, x staged once)
  {
    int g1 = (N_NODES + 127) / 128;
    mfma_gemm1<TyBF ><<<g1, 512, 0, stream>>>(x, W1, hx, flags);
    mfma_gemm1<TyF32><<<g1, 512, 0, stream>>>(x, W1, hx, flags);
  }

  // h = relu(agg(hx) + b1)
  {
    int g = (N_NODES + 7) / 8;
    agg1_kernel<TyBF ><<<g, 256, 0, stream>>>(hx, cnt, offs, adj, dinv, b1, h, flags);
    agg1_kernel<TyF32><<<g, 256, 0, stream>>>(hx, cnt, offs, adj, dinv, b1, h, flags);
  }

  // hml = h @ [Wmu | Wlv]  (MFMA)
  {
    dim3 g2(1, (N_NODES + 127) / 128);
    mfma_gemm2<TyBF ><<<g2, 256, 0, stream>>>(h, Wmu, Wlv, hml, flags);
    mfma_gemm2<TyF32><<<g2, 256, 0, stream>>>(h, Wmu, Wlv, hml, flags);
  }

  // mu, logvar, z
  {
    char* ob = (char*)d_out;
    size_t esz_bf = 2, esz_f32 = 4;
    void* mu_bf  = ob + (size_t)N_NODES * 64 * esz_bf;
    void* lv_bf  = ob + (size_t)N_NODES * 128 * esz_bf;
    void* mu_f32 = ob + (size_t)N_NODES * 64 * esz_f32;
    void* lv_f32 = ob + (size_t)N_NODES * 128 * esz_f32;
    int g = (N_NODES + 7) / 8;
    agg2_kernel<TyBF ><<<g, 256, 0, stream>>>(hml, cnt, offs, adj, dinv, bmu, blv,
                                              eps, mu_bf, lv_bf, z, flags);
    agg2_kernel<TyF32><<<g, 256, 0, stream>>>(hml, cnt, offs, adj, dinv, bmu, blv,
                                              eps, mu_f32, lv_f32, z, flags);
  }

  // out = z @ Wc + bc
  out_gemm<TyBF ><<<N_NODES / 4, 256, 0, stream>>>(z, Wc, bc, d_out, flags);
  out_gemm<TyF32><<<N_NODES / 4, 256, 0, stream>>>(z, Wc, bc, d_out, flags);
}

// Round 6
// 1122.580 us; speedup vs baseline: 1.9657x; 1.1376x over previous
//
#include <hip/hip_runtime.h>

typedef unsigned short u16;
typedef unsigned int u32;

#define N_NODES 100000
#define IN_CH 512
#define HID_CH 256
#define CAP_E 3200000
#define SCAN_NB 391  // ceil(N_NODES/256)

typedef short bf16x8 __attribute__((ext_vector_type(8)));
typedef float f32x4 __attribute__((ext_vector_type(4)));

__device__ __forceinline__ float b2f(u16 u) {
  union { u32 i; float f; } v; v.i = ((u32)u) << 16; return v.f;
}
__device__ __forceinline__ u16 f2b(float f) {
  union { float f; u32 i; } v; v.f = f;
  u32 r = v.i + 0x7fffu + ((v.i >> 16) & 1u);
  return (u16)(r >> 16);
}

struct TyBF {}; struct TyF32 {};
template<class T> struct IsF32;
template<> struct IsF32<TyBF>  { static constexpr int v = 0; };
template<> struct IsF32<TyF32> { static constexpr int v = 1; };

template<class T> __device__ __forceinline__ float ldv(const void* p, size_t i);
template<> __device__ __forceinline__ float ldv<TyBF>(const void* p, size_t i) {
  return b2f(((const u16*)p)[i]);
}
template<> __device__ __forceinline__ float ldv<TyF32>(const void* p, size_t i) {
  return ((const float*)p)[i];
}
template<class T> __device__ __forceinline__ void stv(void* p, size_t i, float v);
template<> __device__ __forceinline__ void stv<TyBF>(void* p, size_t i, float v) {
  ((u16*)p)[i] = f2b(v);
}
template<> __device__ __forceinline__ void stv<TyF32>(void* p, size_t i, float v) {
  ((float*)p)[i] = v;
}

// ---------------- runtime dtype probes ----------------

__global__ void detect_kernel(const u32* __restrict__ xw, const int* __restrict__ ei,
                              int* __restrict__ flags) {
  __shared__ int c1, c2;
  int t = threadIdx.x;  // 256
  if (t == 0) { c1 = 0; c2 = 0; }
  __syncthreads();
  u32 w = xw[t];
  int e = (w >> 7) & 0xFF;
  if (e >= 110 && e <= 135) atomicAdd(&c1, 1);
  if (ei[2 * t + 1] != 0) atomicAdd(&c2, 1);
  __syncthreads();
  if (t == 0) {
    flags[0] = (c1 < 154) ? 1 : 0;
    flags[1] = (c2 > 0) ? 1 : 0;
  }
}

// ---------------- MFMA GEMM 1 (+ overlapped edge count) ----------------
// blocks [0,G1): hx = x @ W1, BM=128 x BN=256, BK=32, 8 waves (2m x 4n).
// blocks [G1,..): count phase of CSR build (only in the DOCOUNT=1 instance,
// so it executes exactly once regardless of dtype). Independent work ->
// count's memory/atomic latency hides under gemm compute.

template<class T, int DOCOUNT>
__global__ __launch_bounds__(512) void gemm1_count(const void* __restrict__ x,
                                                   const void* __restrict__ W1,
                                                   u16* __restrict__ hx,
                                                   const int* __restrict__ flags,
                                                   const int* __restrict__ ei,
                                                   int* __restrict__ cnt,
                                                   int E, int G1) {
  if ((int)blockIdx.x >= G1) {
    if (DOCOUNT) {
      int e = (blockIdx.x - G1) * 512 + threadIdx.x;
      if (e < E) {
        int d = flags[1] ? ei[E + e] : ei[2 * (E + e)];
        if ((u32)d < N_NODES) atomicAdd(&cnt[d], 1);
      }
    }
    return;
  }
  if (flags[0] != IsF32<T>::v) return;
  constexpr int PA = IsF32<T>::v ? 2 : 1;
  __shared__ __align__(16) u16 As[PA][128][40];
  __shared__ __align__(16) u16 Bs[256][40];
  const int t = threadIdx.x;
  const int rowBase = blockIdx.x * 128;
  const int lane = t & 63;
  const int wid = t >> 6;           // 0..7
  const int wm = (wid >> 2) * 64;   // 0,64
  const int wn = (wid & 3) * 64;    // 0,64,128,192
  const int fr = lane & 15;
  const int kc = lane >> 4;

  f32x4 acc[4][4] = {};

  for (int kt = 0; kt < IN_CH / 32; ++kt) {
    // ---- stage A tile (128 rows x 32 k): thread handles 8 floats ----
    {
      int row = t >> 2;
      int c0 = (t & 3) * 8;
      int r = rowBase + row; if (r >= N_NODES) r = N_NODES - 1;
      size_t gb = (size_t)r * IN_CH + kt * 32 + c0;
      if (IsF32<T>::v) {
        u16 th[8], tl[8];
        const float* xp = (const float*)x + gb;
#pragma unroll
        for (int q = 0; q < 2; ++q) {
          float4 v = *(const float4*)(xp + 4 * q);
          float vv[4] = {v.x, v.y, v.z, v.w};
#pragma unroll
          for (int j = 0; j < 4; ++j) {
            u16 hb = f2b(vv[j]);
            th[4 * q + j] = hb;
            tl[4 * q + j] = f2b(vv[j] - b2f(hb));
          }
        }
        *(uint4*)&As[0][row][c0] = *(uint4*)&th[0];
        *(uint4*)&As[1][row][c0] = *(uint4*)&tl[0];
      } else {
        const u16* xp = (const u16*)x + gb;
        *(uint4*)&As[0][row][c0] = *(const uint4*)(xp);
      }
    }
    // ---- stage B tile (32 k x 256 n) -> Bs[n][k] ----
    if (IsF32<T>::v) {
      for (int i = t; i < 2048; i += 512) {
        int k = i >> 6, g = i & 63;
        const float* p = (const float*)W1 + ((size_t)(kt * 32 + k) * HID_CH + g * 4);
        float4 v = *(const float4*)p;
        float vv[4] = {v.x, v.y, v.z, v.w};
#pragma unroll
        for (int j = 0; j < 4; ++j) Bs[g * 4 + j][k] = f2b(vv[j]);
      }
    } else {
      for (int i = t; i < 1024; i += 512) {
        int k = i >> 5, g = i & 31;
        uint4 v = *(const uint4*)((const u16*)W1 + ((size_t)(kt * 32 + k) * HID_CH + g * 8));
        const u16* pv = (const u16*)&v;
#pragma unroll
        for (int j = 0; j < 8; ++j) Bs[g * 8 + j][k] = pv[j];
      }
    }
    __syncthreads();
    // ---- fragments + MFMA ----
    bf16x8 b[4];
#pragma unroll
    for (int ni = 0; ni < 4; ++ni)
      b[ni] = *(const bf16x8*)&Bs[wn + ni * 16 + fr][kc * 8];
#pragma unroll
    for (int mi = 0; mi < 4; ++mi) {
      bf16x8 a0 = *(const bf16x8*)&As[0][wm + mi * 16 + fr][kc * 8];
#pragma unroll
      for (int ni = 0; ni < 4; ++ni)
        acc[mi][ni] = __builtin_amdgcn_mfma_f32_16x16x32_bf16(a0, b[ni], acc[mi][ni], 0, 0, 0);
      if (IsF32<T>::v) {
        bf16x8 a1 = *(const bf16x8*)&As[1][wm + mi * 16 + fr][kc * 8];
#pragma unroll
        for (int ni = 0; ni < 4; ++ni)
          acc[mi][ni] = __builtin_amdgcn_mfma_f32_16x16x32_bf16(a1, b[ni], acc[mi][ni], 0, 0, 0);
      }
    }
    __syncthreads();
  }
  // ---- epilogue: C/D layout col=lane&15, row=(lane>>4)*4+j ----
#pragma unroll
  for (int mi = 0; mi < 4; ++mi) {
#pragma unroll
    for (int ni = 0; ni < 4; ++ni) {
#pragma unroll
      for (int j = 0; j < 4; ++j) {
        int row = rowBase + wm + mi * 16 + kc * 4 + j;
        if (row < N_NODES) {
          int col = wn + ni * 16 + fr;
          hx[(size_t)row * HID_CH + col] = f2b(acc[mi][ni][j]);
        }
      }
    }
  }
}

// ---- parallel 3-phase exclusive scan of cnt -> offs (+ dinv fused) ----

__global__ __launch_bounds__(256) void scan_blk(const int* __restrict__ cnt,
                                                int* __restrict__ offs,
                                                int* __restrict__ bsum) {
  __shared__ int s[256];
  int t = threadIdx.x;
  int i = blockIdx.x * 256 + t;
  int v = (i < N_NODES) ? cnt[i] : 0;
  s[t] = v;
  __syncthreads();
  for (int d = 1; d < 256; d <<= 1) {
    int add = (t >= d) ? s[t - d] : 0;
    __syncthreads();
    s[t] += add;
    __syncthreads();
  }
  if (i < N_NODES) offs[i] = s[t] - v;
  if (t == 255) bsum[blockIdx.x] = s[255];
}

__global__ __launch_bounds__(512) void scan_top(const int* __restrict__ bsum,
                                                int* __restrict__ bpre) {
  __shared__ int s[512];
  int t = threadIdx.x;
  int v = (t < SCAN_NB) ? bsum[t] : 0;
  s[t] = v;
  __syncthreads();
  for (int d = 1; d < 512; d <<= 1) {
    int add = (t >= d) ? s[t - d] : 0;
    __syncthreads();
    s[t] += add;
    __syncthreads();
  }
  if (t < SCAN_NB) bpre[t] = s[t] - v;
}

__global__ __launch_bounds__(256) void scan_add_dinv(int* __restrict__ offs,
                                                     const int* __restrict__ bpre,
                                                     const int* __restrict__ cnt,
                                                     float* __restrict__ dinv) {
  int i = blockIdx.x * 256 + threadIdx.x;
  if (i < N_NODES) {
    offs[i] += bpre[blockIdx.x];
    dinv[i] = rsqrtf((float)(cnt[i] + 1));
  }
}

__global__ void fill_kernel(const int* __restrict__ ei, const int* __restrict__ flags,
                            const int* __restrict__ offs, int* __restrict__ cursor,
                            int* __restrict__ adj, int E) {
  int e = blockIdx.x * blockDim.x + threadIdx.x;
  if (e >= E) return;
  int s, d;
  if (flags[1]) { s = ei[e]; d = ei[E + e]; }
  else          { s = ei[2 * e]; d = ei[2 * (E + e)]; }
  if ((u32)s >= N_NODES || (u32)d >= N_NODES) return;
  int pos = atomicAdd(&cursor[d], 1);
  adj[offs[d] + pos] = s;
}

// ---------------- MFMA GEMM 2: hml = h @ [Wmu | Wlv] ----------------

template<class T>
__global__ __launch_bounds__(256) void mfma_gemm2(const u16* __restrict__ h,
                                                  const void* __restrict__ Wmu,
                                                  const void* __restrict__ Wlv,
                                                  u16* __restrict__ hml,
                                                  const int* __restrict__ flags) {
  if (flags[0] != IsF32<T>::v) return;
  constexpr int PB = IsF32<T>::v ? 2 : 1;
  __shared__ __align__(16) u16 As[128][40];
  __shared__ __align__(16) u16 Bs[PB][128][40];
  const int t = threadIdx.x;
  const int rowBase = blockIdx.y * 128;
  const int lane = t & 63;
  const int wid = t >> 6;
  const int wm = (wid >> 1) * 64;
  const int wn = (wid & 1) * 64;
  const int fr = lane & 15;
  const int kc = lane >> 4;

  f32x4 acc[4][4] = {};

  for (int kt = 0; kt < HID_CH / 32; ++kt) {
    {
      int row = t >> 1;
      int c0 = (t & 1) * 16;
      int r = rowBase + row; if (r >= N_NODES) r = N_NODES - 1;
      const u16* hp = h + (size_t)r * HID_CH + kt * 32 + c0;
      *(uint4*)&As[row][c0]     = *(const uint4*)(hp);
      *(uint4*)&As[row][c0 + 8] = *(const uint4*)(hp + 8);
    }
    for (int i = t; i < 4096; i += 256) {
      int k = i >> 7, n = i & 127;
      const void* W = (n < 64) ? Wmu : Wlv;
      size_t idx = (size_t)(kt * 32 + k) * 64 + (n & 63);
      if (IsF32<T>::v) {
        float v = ((const float*)W)[idx];
        u16 hb = f2b(v);
        Bs[0][n][k] = hb;
        Bs[1][n][k] = f2b(v - b2f(hb));
      } else {
        Bs[0][n][k] = ((const u16*)W)[idx];
      }
    }
    __syncthreads();
    bf16x8 a[4];
#pragma unroll
    for (int mi = 0; mi < 4; ++mi)
      a[mi] = *(const bf16x8*)&As[wm + mi * 16 + fr][kc * 8];
#pragma unroll
    for (int ni = 0; ni < 4; ++ni) {
      bf16x8 b0 = *(const bf16x8*)&Bs[0][wn + ni * 16 + fr][kc * 8];
#pragma unroll
      for (int mi = 0; mi < 4; ++mi)
        acc[mi][ni] = __builtin_amdgcn_mfma_f32_16x16x32_bf16(a[mi], b0, acc[mi][ni], 0, 0, 0);
      if (IsF32<T>::v) {
        bf16x8 b1 = *(const bf16x8*)&Bs[PB - 1][wn + ni * 16 + fr][kc * 8];
#pragma unroll
        for (int mi = 0; mi < 4; ++mi)
          acc[mi][ni] = __builtin_amdgcn_mfma_f32_16x16x32_bf16(a[mi], b1, acc[mi][ni], 0, 0, 0);
      }
    }
    __syncthreads();
  }
#pragma unroll
  for (int mi = 0; mi < 4; ++mi) {
#pragma unroll
    for (int ni = 0; ni < 4; ++ni) {
#pragma unroll
      for (int j = 0; j < 4; ++j) {
        int row = rowBase + wm + mi * 16 + kc * 4 + j;
        if (row < N_NODES) {
          int col = wn + ni * 16 + fr;
          hml[(size_t)row * 128 + col] = f2b(acc[mi][ni][j]);
        }
      }
    }
  }
}

// ---------------- aggregation 1 (256 ch) + bias + relu -> h ----------------
// 2 nodes per wave: half-wave (32 lanes) per node, lane owns 8 channels,
// uint4 (16B) gather per edge, unroll x8. At the measured ~3.8 TB/s
// L2-miss-path ceiling for this random gather (R3/R4/R5 all plateau here).

template<class T>
__global__ __launch_bounds__(256) void agg1_kernel(const u16* __restrict__ hx,
                                                   const int* __restrict__ cnt,
                                                   const int* __restrict__ offs,
                                                   const int* __restrict__ adj,
                                                   const float* __restrict__ dinv,
                                                   const void* __restrict__ b1,
                                                   u16* __restrict__ h,
                                                   const int* __restrict__ flags) {
  if (flags[0] != IsF32<T>::v) return;
  int d = blockIdx.x * 8 + (threadIdx.x >> 5);
  if (d >= N_NODES) return;
  int sub = threadIdx.x & 31;
  const u16* base = hx + sub * 8;
  float a[8] = {};
  int n = cnt[d];
  float dv = dinv[d];
  const int* ent = adj + offs[d];
  int j = 0;
  for (; j + 8 <= n; j += 8) {
    int s[8]; float w[8]; uint4 v[8];
#pragma unroll
    for (int u = 0; u < 8; ++u) s[u] = ent[j + u];
#pragma unroll
    for (int u = 0; u < 8; ++u) w[u] = dv * dinv[s[u]];
#pragma unroll
    for (int u = 0; u < 8; ++u)
      v[u] = *(const uint4*)(base + (size_t)s[u] * HID_CH);
#pragma unroll
    for (int u = 0; u < 8; ++u) {
      a[0] += w[u] * b2f((u16)(v[u].x & 0xffff));
      a[1] += w[u] * b2f((u16)(v[u].x >> 16));
      a[2] += w[u] * b2f((u16)(v[u].y & 0xffff));
      a[3] += w[u] * b2f((u16)(v[u].y >> 16));
      a[4] += w[u] * b2f((u16)(v[u].z & 0xffff));
      a[5] += w[u] * b2f((u16)(v[u].z >> 16));
      a[6] += w[u] * b2f((u16)(v[u].w & 0xffff));
      a[7] += w[u] * b2f((u16)(v[u].w >> 16));
    }
  }
  for (; j < n; ++j) {
    int s = ent[j];
    float w = dv * dinv[s];
    uint4 v = *(const uint4*)(base + (size_t)s * HID_CH);
    a[0] += w * b2f((u16)(v.x & 0xffff));
    a[1] += w * b2f((u16)(v.x >> 16));
    a[2] += w * b2f((u16)(v.y & 0xffff));
    a[3] += w * b2f((u16)(v.y >> 16));
    a[4] += w * b2f((u16)(v.z & 0xffff));
    a[5] += w * b2f((u16)(v.z >> 16));
    a[6] += w * b2f((u16)(v.w & 0xffff));
    a[7] += w * b2f((u16)(v.w >> 16));
  }
  {  // self loop
    float w = dv * dv;
    uint4 v = *(const uint4*)(base + (size_t)d * HID_CH);
    a[0] += w * b2f((u16)(v.x & 0xffff));
    a[1] += w * b2f((u16)(v.x >> 16));
    a[2] += w * b2f((u16)(v.y & 0xffff));
    a[3] += w * b2f((u16)(v.y >> 16));
    a[4] += w * b2f((u16)(v.z & 0xffff));
    a[5] += w * b2f((u16)(v.z >> 16));
    a[6] += w * b2f((u16)(v.w & 0xffff));
    a[7] += w * b2f((u16)(v.w >> 16));
  }
  int c = sub * 8;
  u16 o16[8];
#pragma unroll
  for (int k = 0; k < 8; ++k)
    o16[k] = f2b(fmaxf(a[k] + ldv<T>(b1, c + k), 0.f));
  *(uint4*)(h + (size_t)d * HID_CH + c) = *(uint4*)&o16[0];
}

// ---------------- agg2 + reparam + out GEMM (fused) ----------------
// 2 nodes per wave gather (as before); z (f32) flows through LDS directly
// into out = z @ Wc + bc. No z buffer, no separate out_gemm dispatch.

template<class T>
__global__ __launch_bounds__(256) void agg2_out(const u16* __restrict__ hml,
                                                const int* __restrict__ cnt,
                                                const int* __restrict__ offs,
                                                const int* __restrict__ adj,
                                                const float* __restrict__ dinv,
                                                const void* __restrict__ bmu,
                                                const void* __restrict__ blv,
                                                const void* __restrict__ eps,
                                                const void* __restrict__ Wc,
                                                const void* __restrict__ bc,
                                                void* __restrict__ mu_out,
                                                void* __restrict__ lv_out,
                                                void* __restrict__ out,
                                                const int* __restrict__ flags) {
  if (flags[0] != IsF32<T>::v) return;
  __shared__ float Wcs[64][65];
  __shared__ float zs[8][65];
  int t = threadIdx.x;
  for (int i = t; i < 4096; i += 256) Wcs[i >> 6][i & 63] = ldv<T>(Wc, i);

  int d = blockIdx.x * 8 + (t >> 5);  // grid exact: 100000/8 = 12500
  int sub = t & 31;
  const u16* base = hml + sub * 4;
  float a[4] = {};
  int n = cnt[d];
  float dv = dinv[d];
  const int* ent = adj + offs[d];
  int j = 0;
  for (; j + 8 <= n; j += 8) {
    int s[8]; float w[8]; uint2 v[8];
#pragma unroll
    for (int u = 0; u < 8; ++u) s[u] = ent[j + u];
#pragma unroll
    for (int u = 0; u < 8; ++u) w[u] = dv * dinv[s[u]];
#pragma unroll
    for (int u = 0; u < 8; ++u)
      v[u] = *(const uint2*)(base + (size_t)s[u] * 128);
#pragma unroll
    for (int u = 0; u < 8; ++u) {
      a[0] += w[u] * b2f((u16)(v[u].x & 0xffff));
      a[1] += w[u] * b2f((u16)(v[u].x >> 16));
      a[2] += w[u] * b2f((u16)(v[u].y & 0xffff));
      a[3] += w[u] * b2f((u16)(v[u].y >> 16));
    }
  }
  for (; j < n; ++j) {
    int s = ent[j];
    float w = dv * dinv[s];
    uint2 v = *(const uint2*)(base + (size_t)s * 128);
    a[0] += w * b2f((u16)(v.x & 0xffff));
    a[1] += w * b2f((u16)(v.x >> 16));
    a[2] += w * b2f((u16)(v.y & 0xffff));
    a[3] += w * b2f((u16)(v.y >> 16));
  }
  {  // self loop
    float w = dv * dv;
    uint2 v = *(const uint2*)(base + (size_t)d * 128);
    a[0] += w * b2f((u16)(v.x & 0xffff));
    a[1] += w * b2f((u16)(v.x >> 16));
    a[2] += w * b2f((u16)(v.y & 0xffff));
    a[3] += w * b2f((u16)(v.y >> 16));
  }
  int lane = t & 63;
  int partner = (lane & 32) | (((lane & 31) + 16) & 31);
  float p0 = __shfl(a[0], partner);
  float p1 = __shfl(a[1], partner);
  float p2 = __shfl(a[2], partner);
  float p3 = __shfl(a[3], partner);
  int node = t >> 5;
  if (sub < 16) {
    int c = sub * 4;
    float m[4] = {a[0], a[1], a[2], a[3]};
    float l[4] = {p0, p1, p2, p3};
    size_t o = (size_t)d * 64 + c;
#pragma unroll
    for (int k = 0; k < 4; ++k) {
      m[k] += ldv<T>(bmu, c + k);
      l[k] += ldv<T>(blv, c + k);
      stv<T>(mu_out, o + k, m[k]);
      zs[node][c + k] = m[k] + ldv<T>(eps, o + k) * expf(0.5f * l[k]);
    }
  } else {
    int c = (sub - 16) * 4;
    size_t o = (size_t)d * 64 + c;
#pragma unroll
    for (int k = 0; k < 4; ++k)
      stv<T>(lv_out, o + k, a[k] + ldv<T>(blv, c + k));
  }
  __syncthreads();
  // out: each thread computes 2 columns for its node
  int c0 = sub;
  int c1 = sub + 32;
  float acc0 = ldv<T>(bc, c0);
  float acc1 = ldv<T>(bc, c1);
#pragma unroll
  for (int k = 0; k < 64; ++k) {
    float zv = zs[node][k];
    acc0 += zv * Wcs[k][c0];
    acc1 += zv * Wcs[k][c1];
  }
  size_t ob = (size_t)(blockIdx.x * 8 + node) * 64;
  stv<T>(out, ob + c0, acc0);
  stv<T>(out, ob + c1, acc1);
}

// ---------------- launch ----------------

extern "C" void kernel_launch(void* const* d_in, const int* in_sizes, int n_in,
                              void* d_out, int out_size, void* d_ws, size_t ws_size,
                              hipStream_t stream) {
  const void* x   = d_in[0];
  const int*  ei  = (const int*)d_in[1];
  const void* W1  = d_in[2];
  const void* b1  = d_in[3];
  const void* Wmu = d_in[4];
  const void* bmu = d_in[5];
  const void* Wlv = d_in[6];
  const void* blv = d_in[7];
  const void* Wc  = d_in[8];
  const void* bc  = d_in[9];
  const void* eps = d_in[10];
  int E = in_sizes[1] / 2;

  char* ws = (char*)d_ws;
  int*   flags  = (int*)(ws);                    // 64 B
  int*   cnt    = (int*)(ws + 1024);             // 400 KB
  int*   cursor = (int*)(ws + (512 << 10));      // 400 KB
  int*   offs   = (int*)(ws + (1 << 20));        // 400 KB
  float* dinv   = (float*)(ws + (1536 << 10));   // 400 KB
  int*   bsum   = (int*)(ws + (1536 << 10) + (400 << 10));  // 2 KB
  int*   bpre   = bsum + 512;
  int*   adj    = (int*)(ws + (2 << 20));        // 12.8 MB
  size_t hx_off = (2 << 20) + (size_t)CAP_E * 4;
  u16* hx  = (u16*)(ws + hx_off);                                  // 51.2 MB
  u16* h   = (u16*)(ws + hx_off + (size_t)N_NODES * HID_CH * 2);   // 51.2 MB
  u16* hml = hx;  // hx dead after agg1; reuse (25.6 MB)

  hipMemsetAsync(ws, 0, 2 << 20, stream);

  detect_kernel<<<1, 256, 0, stream>>>((const u32*)x, ei, flags);

  // gemm1 (both dtype variants) with edge-count overlapped in the F32 launch
  {
    int g1 = (N_NODES + 127) / 128;          // 782
    int cb = (E + 511) / 512;                // 6250
    gemm1_count<TyBF, 0><<<g1, 512, 0, stream>>>(x, W1, hx, flags, ei, cnt, E, g1);
    gemm1_count<TyF32, 1><<<g1 + cb, 512, 0, stream>>>(x, W1, hx, flags, ei, cnt, E, g1);
  }

  scan_blk<<<SCAN_NB, 256, 0, stream>>>(cnt, offs, bsum);
  scan_top<<<1, 512, 0, stream>>>(bsum, bpre);
  scan_add_dinv<<<SCAN_NB, 256, 0, stream>>>(offs, bpre, cnt, dinv);
  fill_kernel<<<(E + 255) / 256, 256, 0, stream>>>(ei, flags, offs, cursor, adj, E);

  // h = relu(agg(hx) + b1)
  {
    int g = (N_NODES + 7) / 8;
    agg1_kernel<TyBF ><<<g, 256, 0, stream>>>(hx, cnt, offs, adj, dinv, b1, h, flags);
    agg1_kernel<TyF32><<<g, 256, 0, stream>>>(hx, cnt, offs, adj, dinv, b1, h, flags);
  }

  // hml = h @ [Wmu | Wlv]  (MFMA)
  {
    dim3 g2(1, (N_NODES + 127) / 128);
    mfma_gemm2<TyBF ><<<g2, 256, 0, stream>>>(h, Wmu, Wlv, hml, flags);
    mfma_gemm2<TyF32><<<g2, 256, 0, stream>>>(h, Wmu, Wlv, hml, flags);
  }

  // mu, logvar, z, out (fused)
  {
    char* ob = (char*)d_out;
    size_t esz_bf = 2, esz_f32 = 4;
    void* mu_bf  = ob + (size_t)N_NODES * 64 * esz_bf;
    void* lv_bf  = ob + (size_t)N_NODES * 128 * esz_bf;
    void* mu_f32 = ob + (size_t)N_NODES * 64 * esz_f32;
    void* lv_f32 = ob + (size_t)N_NODES * 128 * esz_f32;
    int g = N_NODES / 8;
    agg2_out<TyBF ><<<g, 256, 0, stream>>>(hml, cnt, offs, adj, dinv, bmu, blv,
                                           eps, Wc, bc, mu_bf, lv_bf, d_out, flags);
    agg2_out<TyF32><<<g, 256, 0, stream>>>(hml, cnt, offs, adj, dinv, bmu, blv,
                                           eps, Wc, bc, mu_f32, lv_f32, d_out, flags);
  }
}